// Round 1
// baseline (267.951 us; speedup 1.0000x reference)
//
#include <hip/hip_runtime.h>
#include <hip/hip_bf16.h>

// CausalSelfAttention: B=4, S=2048, D=1024, H=16, Dh=64. fp32 in/out, bf16 MFMA compute.
//
// Pipeline (all on `stream`):
//   1. convert_x: x fp32 -> bf16 (8192x1024)
//   2. transpose_w: Wq|Wk|Wv -> wqkvt (3072x1024 bf16, N-major), Wo -> wot
//   3. pack_bqkv: [bq|bk|bv] -> fp32 (3072)
//   4. gemm256: qkv = xb @ [Wq|Wk|Wv] + b  -> qk bf16 (8192x2048, Q pre-scaled by
//               0.125*log2e) + vt (B,H,Dh,S) scatter.
//               NEW (R12): 256x256 tile, BK=64, 8 waves, 8-phase schedule with
//               counted vmcnt(4) (never drain-0 in loop), XOR-swizzled LDS reads,
//               setprio around MFMA clusters (guide T2+T3+T4+T5, m201 template).
//   5. attn: flash attention, max-free softmax, one barrier/round, DMA double-buffered
//            XOR-swizzled K/V LDS (R11 winner, unchanged)
//   6. gemm_bt<1>: out = attn @ Wo + bo     -> fp32 d_out (old 128^2 kernel, unchanged)

typedef __bf16 bf16x8 __attribute__((ext_vector_type(8)));
typedef float f32x4 __attribute__((ext_vector_type(4)));
typedef unsigned short u16;

__device__ __forceinline__ u16 f2b(float f) {
    __hip_bfloat16 h = __float2bfloat16(f);
    return __builtin_bit_cast(unsigned short, h);
}

__device__ __forceinline__ f32x4 mfma16(bf16x8 a, bf16x8 b, f32x4 c) {
    return __builtin_amdgcn_mfma_f32_16x16x32_bf16(a, b, c, 0, 0, 0);
}

typedef const __attribute__((address_space(1))) unsigned int* gas1_t;
typedef __attribute__((address_space(3))) unsigned int* las3_t;
// Async global->LDS, 16B/lane. LDS dest = wave-uniform base + lane*16 (m104/m108).
__device__ __forceinline__ void gld16(const void* g, void* l) {
    __builtin_amdgcn_global_load_lds((gas1_t)g, (las3_t)l, 16, 0, 0);
}

// ---------------------------------------------------------------- conversions
__global__ __launch_bounds__(256) void convert_x(const float* __restrict__ x,
                                                 u16* __restrict__ xb, int n4) {
    int i = blockIdx.x * 256 + threadIdx.x;
    if (i < n4) {
        float4 v = ((const float4*)x)[i];
        ushort4 u;
        u.x = f2b(v.x); u.y = f2b(v.y); u.z = f2b(v.z); u.w = f2b(v.w);
        ((ushort4*)xb)[i] = u;
    }
}

// W (K=1024 rows, N=1024 cols) fp32 -> Wt (N,K) bf16. z selects matrix.
__global__ __launch_bounds__(256) void transpose_w(const float* __restrict__ Wq,
                                                   const float* __restrict__ Wk,
                                                   const float* __restrict__ Wv,
                                                   const float* __restrict__ Wo,
                                                   u16* __restrict__ wqkvt,
                                                   u16* __restrict__ wot) {
    const int z = blockIdx.z;
    const float* src = (z == 0) ? Wq : (z == 1) ? Wk : (z == 2) ? Wv : Wo;
    u16* dst = (z == 3) ? wot : (wqkvt + (size_t)z * 1024 * 1024);
    __shared__ float tile[32][33];
    const int tx = threadIdx.x, ty = threadIdx.y;  // block (32,8)
    const int nbase = blockIdx.x * 32, kbase = blockIdx.y * 32;
    for (int j = 0; j < 4; ++j)
        tile[ty + j * 8][tx] = src[(size_t)(kbase + ty + j * 8) * 1024 + nbase + tx];
    __syncthreads();
    for (int j = 0; j < 4; ++j)
        dst[(size_t)(nbase + ty + j * 8) * 1024 + kbase + tx] = f2b(tile[tx][ty + j * 8]);
}

__global__ __launch_bounds__(256) void pack_bqkv(const float* __restrict__ bq,
                                                 const float* __restrict__ bk,
                                                 const float* __restrict__ bv,
                                                 float* __restrict__ bqkv) {
    int i = blockIdx.x * 256 + threadIdx.x;  // 3072 total
    bqkv[i] = (i < 1024) ? bq[i] : (i < 2048) ? bk[i - 1024] : bv[i - 2048];
}

// ---------------------------------------------------------------- GEMM 256^2 8-phase
// C(M,N) = A(M,K) @ Bt(N,K)^T + bias, QKV epilogue. BM=BN=256, BK=64, 512 thr = 8 waves.
// LDS 128 KiB: As/Bs[2 dbuf][256][64] bf16, rows 128B.
// Per K-tile: 4 phases, each computes one 128x128 C-quadrant (waves tiled 4M x 2N,
// 32x64 each = 16 MFMA/phase/wave). Quadrant order (0,0)->(1,0)->(1,1)->(0,1);
// stage order for K-tile t+1 into buf^1: A0,B0,A1,B1 (one half = 128x64 = 2 gld16/thr
// per phase). Counted vmcnt(4) at end of phases 1,2,4 provably retires exactly the
// half-tile needed by the next phase's ds_reads (derivation in session journal):
//   steady-state queue after ph4 vmcnt(4): [A1(t+1),B1(t+1)] = 4 loads.
// LDS swizzle: 16B-chunk c stored at c^(row&7) -> ds_read_b128 hits all 8 bank
// quads (conflict-free); gld16 dest stays linear, SOURCE pre-swizzled (rule #21).
__global__ __launch_bounds__(512, 2) void gemm256(const u16* __restrict__ A,
                                                  const u16* __restrict__ Bt,
                                                  const float* __restrict__ bias,
                                                  u16* __restrict__ qkout,
                                                  u16* __restrict__ vtout,
                                                  int K) {
    const int tid = threadIdx.x;
    const int l = tid & 63;
    const int w = tid >> 6;   // 0..7
    const int mw = w >> 1;    // 0..3: 32-row slice within the 128-row quadrant
    const int nw = w & 1;     // 0..1: 64-col slice within the 128-col quadrant
    const int mrow = l & 15;
    const int g = l >> 4;     // 0..3
    const int tileM = blockIdx.x * 256;
    const int tileN = blockIdx.y * 256;

    __shared__ u16 As[2][256 * 64];
    __shared__ u16 Bs[2][256 * 64];

    // read-side swizzled chunk offsets (u16 elems within 64-elem row); c = ks*4+g
    const int swz = mrow & 7;
    const int co0 = ((0 + g) ^ swz) * 8;
    const int co1 = ((4 + g) ^ swz) * 8;

    // stage-side: lane l covers slab row (l>>3), LDS chunk l&7 -> global chunk gc
    // (involution: LDS[r][c] holds global[r][c^(r&7)], slab base rows are %8==0)
    const int gc = (l & 7) ^ (l >> 3);
    const u16* aStage = A + (size_t)(tileM + (l >> 3)) * K + gc * 8;
    const u16* bStage = Bt + (size_t)(tileN + (l >> 3)) * K + gc * 8;

    bf16x8 aR[2][2];  // [i2][ks] current A 32-row slice
    bf16x8 bR[4][2];  // [in][ks] current B 64-col slice
    f32x4 acc00[2][4] = {}, acc10[2][4] = {}, acc11[2][4] = {}, acc01[2][4] = {};

    auto stageA = [&](int hh, int tt, int nb) {
        const u16* p = aStage + (size_t)(hh * 128 + w * 16) * K + tt * 64;
        gld16(p, &As[nb][(hh * 16 + w * 2) * 512]);
        gld16(p + (size_t)8 * K, &As[nb][(hh * 16 + w * 2 + 1) * 512]);
    };
    auto stageB = [&](int hh, int tt, int nb) {
        const u16* p = bStage + (size_t)(hh * 128 + w * 16) * K + tt * 64;
        gld16(p, &Bs[nb][(hh * 16 + w * 2) * 512]);
        gld16(p + (size_t)8 * K, &Bs[nb][(hh * 16 + w * 2 + 1) * 512]);
    };
    auto lda = [&](int qa, int buf) {
#pragma unroll
        for (int i2 = 0; i2 < 2; ++i2) {
            const int r = qa * 128 + mw * 32 + i2 * 16 + mrow;  // r&7 == mrow&7
            aR[i2][0] = *(const bf16x8*)&As[buf][r * 64 + co0];
            aR[i2][1] = *(const bf16x8*)&As[buf][r * 64 + co1];
        }
    };
    auto ldb = [&](int qb, int buf) {
#pragma unroll
        for (int in = 0; in < 4; ++in) {
            const int r = qb * 128 + nw * 64 + in * 16 + mrow;  // r&7 == mrow&7
            bR[in][0] = *(const bf16x8*)&Bs[buf][r * 64 + co0];
            bR[in][1] = *(const bf16x8*)&Bs[buf][r * 64 + co1];
        }
    };
    auto mm = [&](f32x4 (&C)[2][4]) {
#pragma unroll
        for (int ks = 0; ks < 2; ++ks)
#pragma unroll
            for (int i2 = 0; i2 < 2; ++i2)
#pragma unroll
                for (int in = 0; in < 4; ++in)
                    C[i2][in] = mfma16(aR[i2][ks], bR[in][ks], C[i2][in]);
    };
    auto barSB = [&]() {
        __builtin_amdgcn_sched_barrier(0);
        __builtin_amdgcn_s_barrier();
        __builtin_amdgcn_sched_barrier(0);
    };

    // prologue: K-tile 0 -> buf 0 (order A0,B0,A1,B1); vmcnt(4) retires A0,B0
    stageA(0, 0, 0); stageB(0, 0, 0); stageA(1, 0, 0); stageB(1, 0, 0);
    asm volatile("s_waitcnt vmcnt(4)" ::: "memory");
    barSB();

    const int NT = K >> 6;
    for (int t = 0; t < NT; ++t) {
        const int buf = t & 1, nb = buf ^ 1;
        const int tp = (t + 1 < NT) ? t + 1 : t;  // last tile: clamped dummy re-stage

        // -- phase 1: quadrant (0,0); stage A-half0(t+1)
        lda(0, buf); ldb(0, buf);
        stageA(0, tp, nb);
        barSB();
        asm volatile("s_waitcnt lgkmcnt(0)" ::: "memory");
        __builtin_amdgcn_sched_barrier(0);
        __builtin_amdgcn_s_setprio(1);
        mm(acc00);
        __builtin_amdgcn_s_setprio(0);
        asm volatile("s_waitcnt vmcnt(4)" ::: "memory");  // retires A1(t): ph2 reads it
        barSB();

        // -- phase 2: quadrant (1,0); stage B-half0(t+1)
        lda(1, buf);
        stageB(0, tp, nb);
        barSB();
        asm volatile("s_waitcnt lgkmcnt(0)" ::: "memory");
        __builtin_amdgcn_sched_barrier(0);
        __builtin_amdgcn_s_setprio(1);
        mm(acc10);
        __builtin_amdgcn_s_setprio(0);
        asm volatile("s_waitcnt vmcnt(4)" ::: "memory");  // retires B1(t): ph3 reads it
        barSB();

        // -- phase 3: quadrant (1,1); stage A-half1(t+1)
        ldb(1, buf);
        stageA(1, tp, nb);
        barSB();
        asm volatile("s_waitcnt lgkmcnt(0)" ::: "memory");
        __builtin_amdgcn_sched_barrier(0);
        __builtin_amdgcn_s_setprio(1);
        mm(acc11);
        __builtin_amdgcn_s_setprio(0);
        barSB();  // ph4 re-reads A0(t): still resident, no vmcnt needed

        // -- phase 4: quadrant (0,1); stage B-half1(t+1)
        lda(0, buf);
        stageB(1, tp, nb);
        barSB();
        asm volatile("s_waitcnt lgkmcnt(0)" ::: "memory");
        __builtin_amdgcn_sched_barrier(0);
        __builtin_amdgcn_s_setprio(1);
        mm(acc01);
        __builtin_amdgcn_s_setprio(0);
        asm volatile("s_waitcnt vmcnt(4)" ::: "memory");  // retires A0,B0(t+1): ph1 needs
        barSB();
    }

    // epilogue: C/D layout row=(l>>4)*4+r, col=l&15 per fragment [m89/m91].
    // tileN granularity 256 => whole block uniformly Q (<1024), K (<2048) or V.
    const int rbase = (l >> 4) * 4;
    auto epi = [&](f32x4 (&C)[2][4], int qa, int qb) {
#pragma unroll
        for (int i2 = 0; i2 < 2; ++i2) {
#pragma unroll
            for (int in = 0; in < 4; ++in) {
                const int gm0 = tileM + qa * 128 + mw * 32 + i2 * 16 + rbase;
                const int gn = tileN + qb * 128 + nw * 64 + in * 16 + (l & 15);
                const float bv_ = bias[gn];
                const f32x4 a = C[i2][in];
                if (tileN < 2048) {
                    // fold softmax scale * log2e into Q
                    const float qs = (tileN < 1024) ? 0.125f * 1.4426950408889634f : 1.0f;
#pragma unroll
                    for (int r = 0; r < 4; ++r)
                        qkout[(size_t)(gm0 + r) * 2048 + gn] = f2b((a[r] + bv_) * qs);
                } else {
                    const int b = gm0 >> 11, s0 = gm0 & 2047;
                    const int gn2 = gn - 2048;
                    const int h = gn2 >> 6, dh = gn2 & 63;
                    ushort4 u;
                    u.x = f2b(a[0] + bv_); u.y = f2b(a[1] + bv_);
                    u.z = f2b(a[2] + bv_); u.w = f2b(a[3] + bv_);
                    *(ushort4*)&vtout[((size_t)((b * 16 + h) * 64 + dh)) * 2048 + s0] = u;
                }
            }
        }
    };
    epi(acc00, 0, 0); epi(acc10, 1, 0); epi(acc11, 1, 1); epi(acc01, 0, 1);
}

// ---------------------------------------------------------------- GEMM (old 128^2, MODE 1 only)
// C(M,N) = A(M,K) @ Bt(N,K)^T + bias. 128x128 tile, BK=32, 256 thr = 4 waves.
template <int MODE>
__global__ __launch_bounds__(256, 2) void gemm_bt(const u16* __restrict__ A,
                                                  const u16* __restrict__ Bt,
                                                  const float* __restrict__ bias,
                                                  void* __restrict__ Cout,
                                                  void* __restrict__ Cout2,
                                                  int M, int N, int K, int ldc) {
    const int tid = threadIdx.x;
    const int l = tid & 63;
    const int w = tid >> 6;
    const int tileM = blockIdx.x * 128;
    const int tileN = blockIdx.y * 128;

    __shared__ u16 As[2][128 * 32];  // [buf][row][k] stride 32
    __shared__ u16 Bs[2][128 * 32];

    const int srow = l >> 2;
    const int schunk = l & 3;
    const int mrow = l & 15;
    const int g8 = (l >> 4) * 8;
    const int waveM = (w & 1) * 64;
    const int waveN = (w >> 1) * 64;

    const u16* a0 = A + (size_t)(tileM + w * 32 + srow) * K + schunk * 8;
    const u16* a1 = A + (size_t)(tileM + w * 32 + 16 + srow) * K + schunk * 8;
    const u16* b0 = Bt + (size_t)(tileN + w * 32 + srow) * K + schunk * 8;
    const u16* b1 = Bt + (size_t)(tileN + w * 32 + 16 + srow) * K + schunk * 8;

    f32x4 acc[4][4] = {};

    gld16(a0, &As[0][(w * 2) * 512]);
    gld16(a1, &As[0][(w * 2 + 1) * 512]);
    gld16(b0, &Bs[0][(w * 2) * 512]);
    gld16(b1, &Bs[0][(w * 2 + 1) * 512]);
    __syncthreads();

    for (int k0 = 0; k0 < K; k0 += 32) {
        const int cur = (k0 >> 5) & 1;
        if (k0 + 32 < K) {
            const int nb = cur ^ 1;
            gld16(a0 + k0 + 32, &As[nb][(w * 2) * 512]);
            gld16(a1 + k0 + 32, &As[nb][(w * 2 + 1) * 512]);
            gld16(b0 + k0 + 32, &Bs[nb][(w * 2) * 512]);
            gld16(b1 + k0 + 32, &Bs[nb][(w * 2 + 1) * 512]);
        }

        bf16x8 af[4], bf[4];
        for (int im = 0; im < 4; ++im)
            af[im] = *(const bf16x8*)&As[cur][(waveM + im * 16 + mrow) * 32 + g8];
        for (int in = 0; in < 4; ++in)
            bf[in] = *(const bf16x8*)&Bs[cur][(waveN + in * 16 + mrow) * 32 + g8];
        for (int im = 0; im < 4; ++im)
            for (int in = 0; in < 4; ++in)
                acc[im][in] = mfma16(af[im], bf[in], acc[im][in]);
        __syncthreads();
    }

    const int rbase = (l >> 4) * 4;
    for (int im = 0; im < 4; ++im) {
        for (int in = 0; in < 4; ++in) {
            const int gm0 = tileM + waveM + im * 16 + rbase;
            const int gn = tileN + waveN + in * 16 + (l & 15);
            const float bv_ = bias[gn];
            if (MODE == 1) {
                float* out = (float*)Cout;
                for (int r = 0; r < 4; ++r)
                    out[(size_t)(gm0 + r) * ldc + gn] = acc[im][in][r] + bv_;
            } else if (tileN < 2048) {
                const float qs = (tileN < 1024) ? 0.125f * 1.4426950408889634f : 1.0f;
                u16* out = (u16*)Cout;
                for (int r = 0; r < 4; ++r)
                    out[(size_t)(gm0 + r) * 2048 + gn] = f2b((acc[im][in][r] + bv_) * qs);
            } else {
                u16* out = (u16*)Cout2;
                const int b = gm0 >> 11, s0 = gm0 & 2047;
                const int gn2 = gn - 2048;
                const int h = gn2 >> 6, dh = gn2 & 63;
                ushort4 u;
                u.x = f2b(acc[im][in][0] + bv_);
                u.y = f2b(acc[im][in][1] + bv_);
                u.z = f2b(acc[im][in][2] + bv_);
                u.w = f2b(acc[im][in][3] + bv_);
                *(ushort4*)&out[((size_t)((b * 16 + h) * 64 + dh)) * 2048 + s0] = u;
            }
        }
    }
}

// ---------------------------------------------------------------- flash attention
// R11 winner, unchanged: 256 thr = 4 waves, 128 queries/block, ONE barrier/round,
// K/V staged by global_load_lds DMA into double-buffered XOR-swizzled LDS tiles,
// max-free softmax with epilogue-only denominator reduction.
__global__ __launch_bounds__(256, 2) void attn_kernel(const u16* __restrict__ qk,
                                                      const u16* __restrict__ vt,
                                                      u16* __restrict__ attn) {
    const int bh = blockIdx.x;
    const int qt = 15 - (int)blockIdx.y;  // big q-tiles launch first
    const int b = bh >> 4, h = bh & 15;
    const int q0 = qt * 128;
    const int tid = threadIdx.x, l = tid & 63, w = tid >> 6;
    const int q = l & 15;   // query column within group
    const int g = l >> 4;   // k-group
    const int g8 = g * 8;

    __shared__ u16 Ks[2][64 * 64];  // [buf][key][dh]   XOR-swizzled chunks
    __shared__ u16 Vs[2][64 * 64];  // [buf][dh][key]   XOR-swizzled chunks
    __shared__ u16 Ps[128 * 72];    // Q staging, then per-wave P slabs [query][key]

    const int sr8 = l >> 3;
    const int gc = (l & 7) ^ sr8;
    const u16* kgl = qk + (size_t)(b * 2048 + w * 16 + sr8) * 2048 + 1024 + h * 64 + gc * 8;
    const u16* vgl = vt + (size_t)(bh * 64 + w * 16 + sr8) * 2048 + gc * 8;

    for (int i = 0; i < 4; ++i) {
        const int idx = i * 256 + tid;
        const int row = idx >> 3, ch = idx & 7;
        *(uint4*)&Ps[row * 72 + ch * 8] =
            *(const uint4*)&qk[(size_t)(b * 2048 + q0 + row) * 2048 + h * 64 + ch * 8];
    }
    for (int j = 0; j < 2; ++j) {
        gld16(kgl + (size_t)(j * 8) * 2048, &Ks[0][(w * 16 + j * 8) * 64]);
        gld16(vgl + (size_t)(j * 8) * 2048, &Vs[0][(w * 16 + j * 8) * 64]);
    }
    __syncthreads();

    bf16x8 qb[2][2];
    for (int c = 0; c < 2; ++c) {
        qb[c][0] = *(const bf16x8*)&Ps[(w * 32 + c * 16 + q) * 72 + g8];
        qb[c][1] = *(const bf16x8*)&Ps[(w * 32 + c * 16 + q) * 72 + 32 + g8];
    }

    const int cl0 = ((g) ^ (q & 7)) * 8;
    const int cl1 = ((4 + g) ^ (q & 7)) * 8;

    float li[2] = {0.f, 0.f};
    f32x4 o[2][4] = {};
    const int tmax = 2 * qt + 1;
    const int tdiag = (q0 + w * 32 + 31) >> 6;

    for (int t = 0; t <= tmax; ++t) {
        const int tp = (t < tmax) ? t + 1 : tmax;
        const int nb = (t + 1) & 1;
        for (int j = 0; j < 2; ++j) {
            gld16(kgl + (size_t)(tp * 64 + j * 8) * 2048, &Ks[nb][(w * 16 + j * 8) * 64]);
            gld16(vgl + (size_t)(j * 8) * 2048 + tp * 64, &Vs[nb][(w * 16 + j * 8) * 64]);
        }

        if (t <= tdiag) {
            const int cb0 = t & 1;
            const int kv0 = t * 64;
            const u16* ks = &Ks[cb0][0];
            const u16* vs = &Vs[cb0][0];

            f32x4 st[2][4] = {};
            for (int cb = 0; cb < 4; ++cb) {
                bf16x8 ka0 = *(const bf16x8*)&ks[(cb * 16 + q) * 64 + cl0];
                bf16x8 ka1 = *(const bf16x8*)&ks[(cb * 16 + q) * 64 + cl1];
                st[0][cb] = mfma16(ka0, qb[0][0], st[0][cb]);
                st[1][cb] = mfma16(ka0, qb[1][0], st[1][cb]);
                st[0][cb] = mfma16(ka1, qb[0][1], st[0][cb]);
                st[1][cb] = mfma16(ka1, qb[1][1], st[1][cb]);
            }
            for (int c = 0; c < 2; ++c) {
                if (t == tdiag) {
                    const int qg = q0 + w * 32 + c * 16 + q;
                    for (int cb = 0; cb < 4; ++cb)
                        for (int r = 0; r < 4; ++r) {
                            const int key = kv0 + cb * 16 + g * 4 + r;
                            if (key > qg) st[c][cb][r] = -1e30f;
                        }
                }
                float ps = 0.f;
                for (int cb = 0; cb < 4; ++cb)
                    for (int r = 0; r < 4; ++r) {
                        const float p = __builtin_amdgcn_exp2f(st[c][cb][r]);
                        st[c][cb][r] = p;
                        ps += p;
                    }
                li[c] += ps;
                for (int cb = 0; cb < 4; ++cb) {
                    ushort4 u;
                    u.x = f2b(st[c][cb][0]); u.y = f2b(st[c][cb][1]);
                    u.z = f2b(st[c][cb][2]); u.w = f2b(st[c][cb][3]);
                    *(ushort4*)&Ps[(w * 32 + c * 16 + q) * 72 + cb * 16 + g * 4] = u;
                }
            }
            __builtin_amdgcn_s_waitcnt(0xC07F);  // lgkmcnt(0)
            for (int cb = 0; cb < 4; ++cb) {
                bf16x8 va0 = *(const bf16x8*)&vs[(cb * 16 + q) * 64 + cl0];
                bf16x8 va1 = *(const bf16x8*)&vs[(cb * 16 + q) * 64 + cl1];
                bf16x8 pb00 = *(const bf16x8*)&Ps[(w * 32 + q) * 72 + g8];
                bf16x8 pb01 = *(const bf16x8*)&Ps[(w * 32 + q) * 72 + 32 + g8];
                bf16x8 pb10 = *(const bf16x8*)&Ps[(w * 32 + 16 + q) * 72 + g8];
                bf16x8 pb11 = *(const bf16x8*)&Ps[(w * 32 + 16 + q) * 72 + 32 + g8];
                o[0][cb] = mfma16(va0, pb00, o[0][cb]);
                o[1][cb] = mfma16(va0, pb10, o[1][cb]);
                o[0][cb] = mfma16(va1, pb01, o[0][cb]);
                o[1][cb] = mfma16(va1, pb11, o[1][cb]);
            }
        }
        __syncthreads();
    }

    for (int c = 0; c < 2; ++c) {
        float ps = li[c];
        ps += __shfl_xor(ps, 16);
        ps += __shfl_xor(ps, 32);
        const float inv = 1.0f / ps;
        const size_t tok = (size_t)(b * 2048 + q0 + w * 32 + c * 16 + q);
        for (int cb = 0; cb < 4; ++cb) {
            ushort4 u;
            u.x = f2b(o[c][cb][0] * inv); u.y = f2b(o[c][cb][1] * inv);
            u.z = f2b(o[c][cb][2] * inv); u.w = f2b(o[c][cb][3] * inv);
            *(ushort4*)&attn[tok * 1024 + h * 64 + cb * 16 + g * 4] = u;
        }
    }
}

// ---------------------------------------------------------------- launch
extern "C" void kernel_launch(void* const* d_in, const int* in_sizes, int n_in,
                              void* d_out, int out_size, void* d_ws, size_t ws_size,
                              hipStream_t stream) {
    const float* x  = (const float*)d_in[0];
    const float* Wq = (const float*)d_in[1];
    const float* bq = (const float*)d_in[2];
    const float* Wk = (const float*)d_in[3];
    const float* bk = (const float*)d_in[4];
    const float* Wv = (const float*)d_in[5];
    const float* bv = (const float*)d_in[6];
    const float* Wo = (const float*)d_in[7];
    const float* bo = (const float*)d_in[8];
    float* out = (float*)d_out;

    char* ws = (char*)d_ws;
    size_t off = 0;
    auto alloc = [&](size_t bytes) -> void* {
        void* p = ws + off;
        off += (bytes + 255) & ~(size_t)255;
        return p;
    };
    u16*   xb    = (u16*)alloc(8192ull * 1024 * 2);   // x bf16
    u16*   wqkvt = (u16*)alloc(3072ull * 1024 * 2);   // [Wq|Wk|Wv]^T (N,K)
    u16*   wot   = (u16*)alloc(1024ull * 1024 * 2);   // Wo^T
    float* bqkv  = (float*)alloc(3072ull * 4);
    u16*   qk    = (u16*)alloc(8192ull * 2048 * 2);   // [q|k] (token, 2048)
    u16*   vt    = (u16*)alloc(8192ull * 1024 * 2);   // V^T (B,H,Dh,S)
    u16*   attn  = (u16*)alloc(8192ull * 1024 * 2);   // attention out (token, D)

    convert_x<<<8192, 256, 0, stream>>>(x, xb, 8192 * 1024 / 4);
    transpose_w<<<dim3(32, 32, 4), dim3(32, 8), 0, stream>>>(Wq, Wk, Wv, Wo, wqkvt, wot);
    pack_bqkv<<<12, 256, 0, stream>>>(bq, bk, bv, bqkv);
    gemm256<<<dim3(32, 12), 512, 0, stream>>>(xb, wqkvt, bqkv, qk, vt, 1024);
    attn_kernel<<<dim3(64, 16), 256, 0, stream>>>(qk, vt, attn);
    gemm_bt<1><<<dim3(64, 8), 256, 0, stream>>>(attn, wot, bo, out, nullptr, 8192, 1024, 1024, 1024);
}

// Round 2
// 258.098 us; speedup vs baseline: 1.0382x; 1.0382x over previous
//
#include <hip/hip_runtime.h>
#include <hip/hip_bf16.h>

// CausalSelfAttention: B=4, S=2048, D=1024, H=16, Dh=64. fp32 in/out, bf16 MFMA compute.
//
// Pipeline (all on `stream`):
//   1. convert_x: x fp32 -> bf16 (8192x1024)
//   2. transpose_w: Wq|Wk|Wv -> wqkvt (3072x1024 bf16, N-major), Wo -> wot
//   3. pack_bqkv: [bq|bk|bv] -> fp32 (3072)
//   4. gemm256 v2: qkv = xb @ [Wq|Wk|Wv] + b -> qk bf16 (Q pre-scaled) + vt scatter.
//      R13: 256x256, BK=64, 8 waves. TWO ks-split phases per K-tile, each:
//      {vmcnt(4); s_barrier; fence; 12 ds_read_b128; 4 gld16 stage; 32 MFMA}.
//      NO sched_barrier / explicit lgkm pinning (R12 post-mortem: m141-style
//      over-pinning serialized drain->MFMA, 96us). Compiler interleaves reads
//      with MFMA via its own fine-grained lgkmcnt. Counted vmcnt only, never 0
//      in-loop. LDS [buf][ks][256][32] with chunk^(row&3) swizzle (conflict-free).
//   5. attn: flash attention (R11 winner, unchanged)
//   6. gemm_bt<1>: out = attn @ Wo + bo -> fp32 d_out (old 128^2 kernel, unchanged)

typedef __bf16 bf16x8 __attribute__((ext_vector_type(8)));
typedef float f32x4 __attribute__((ext_vector_type(4)));
typedef unsigned short u16;

__device__ __forceinline__ u16 f2b(float f) {
    __hip_bfloat16 h = __float2bfloat16(f);
    return __builtin_bit_cast(unsigned short, h);
}

__device__ __forceinline__ f32x4 mfma16(bf16x8 a, bf16x8 b, f32x4 c) {
    return __builtin_amdgcn_mfma_f32_16x16x32_bf16(a, b, c, 0, 0, 0);
}

typedef const __attribute__((address_space(1))) unsigned int* gas1_t;
typedef __attribute__((address_space(3))) unsigned int* las3_t;
// Async global->LDS, 16B/lane. LDS dest = wave-uniform base + lane*16 (m104/m108).
__device__ __forceinline__ void gld16(const void* g, void* l) {
    __builtin_amdgcn_global_load_lds((gas1_t)g, (las3_t)l, 16, 0, 0);
}

// ---------------------------------------------------------------- conversions
__global__ __launch_bounds__(256) void convert_x(const float* __restrict__ x,
                                                 u16* __restrict__ xb, int n4) {
    int i = blockIdx.x * 256 + threadIdx.x;
    if (i < n4) {
        float4 v = ((const float4*)x)[i];
        ushort4 u;
        u.x = f2b(v.x); u.y = f2b(v.y); u.z = f2b(v.z); u.w = f2b(v.w);
        ((ushort4*)xb)[i] = u;
    }
}

// W (K=1024 rows, N=1024 cols) fp32 -> Wt (N,K) bf16. z selects matrix.
__global__ __launch_bounds__(256) void transpose_w(const float* __restrict__ Wq,
                                                   const float* __restrict__ Wk,
                                                   const float* __restrict__ Wv,
                                                   const float* __restrict__ Wo,
                                                   u16* __restrict__ wqkvt,
                                                   u16* __restrict__ wot) {
    const int z = blockIdx.z;
    const float* src = (z == 0) ? Wq : (z == 1) ? Wk : (z == 2) ? Wv : Wo;
    u16* dst = (z == 3) ? wot : (wqkvt + (size_t)z * 1024 * 1024);
    __shared__ float tile[32][33];
    const int tx = threadIdx.x, ty = threadIdx.y;  // block (32,8)
    const int nbase = blockIdx.x * 32, kbase = blockIdx.y * 32;
    for (int j = 0; j < 4; ++j)
        tile[ty + j * 8][tx] = src[(size_t)(kbase + ty + j * 8) * 1024 + nbase + tx];
    __syncthreads();
    for (int j = 0; j < 4; ++j)
        dst[(size_t)(nbase + ty + j * 8) * 1024 + kbase + tx] = f2b(tile[tx][ty + j * 8]);
}

__global__ __launch_bounds__(256) void pack_bqkv(const float* __restrict__ bq,
                                                 const float* __restrict__ bk,
                                                 const float* __restrict__ bv,
                                                 float* __restrict__ bqkv) {
    int i = blockIdx.x * 256 + threadIdx.x;  // 3072 total
    bqkv[i] = (i < 1024) ? bq[i] : (i < 2048) ? bk[i - 1024] : bv[i - 2048];
}

// ---------------------------------------------------------------- GEMM 256^2 v2
// C(M,N) = A(M,K) @ Bt(N,K)^T + bias, QKV epilogue. BM=BN=256, BK=64, 512 thr = 8 waves.
// Waves 4M x 2N: wave = 64 rows x 128 cols; acc[4][8] f32x4 (128 AGPR).
// LDS 128 KiB: As/Bs[2 dbuf][2 ks][256 rows][32 u16]; row = 64B = 4 x 16B chunks.
// Swizzle: LDS[row][c] = global[row][ks*32 + (c^(row&3))*8]. Frag read offset is
// per-lane constant ((l>>4)^(l&3))*16B; a wave's b128 frag read covers a contiguous
// 1KB region exactly once -> conflict-free. Stage: 4 gld16/wave/phase (A h0/h1,
// B h0/h1 of one ks-half of tile t+1), 1KB each, linear LDS dest, pre-swizzled
// global source (both-sides-or-neither, rule #21).
// vmcnt protocol (per wave, 4 loads/phase): queue at phase top always holds
// [prev-phase 4, this-ks 4-from-2-phases-ago already retired...] -> vmcnt(4)
// retires exactly the 4 loads this phase reads. Slack = 2 phases (~2600 cyc) > HBM.
__global__ __launch_bounds__(512, 2) void gemm256(const u16* __restrict__ A,
                                                  const u16* __restrict__ Bt,
                                                  const float* __restrict__ bias,
                                                  u16* __restrict__ qkout,
                                                  u16* __restrict__ vtout,
                                                  int K) {
    const int tid = threadIdx.x;
    const int l = tid & 63;
    const int w = tid >> 6;   // 0..7
    const int mw = w >> 1;    // 0..3: wave rows = mw*64..mw*64+63
    const int nw = w & 1;     // 0..1: wave cols = nw*128..nw*128+127
    const int mrow = l & 15;
    const int tileM = blockIdx.x * 256;
    const int tileN = blockIdx.y * 256;

    __shared__ u16 As[2][2][256 * 32];  // [buf][ks][row*32+col]
    __shared__ u16 Bs[2][2][256 * 32];

    // read-side swizzled chunk offset (u16 units): chunk = (l>>4) ^ (l&3)
    // (valid for all frag rows r = 16*base + mrow since r&3 == l&3)
    const int rco = ((l >> 4) ^ (l & 3)) * 8;

    // stage-side: lane covers row (l>>2) of a 16-row slab, LDS chunk l&3,
    // global chunk (l&3)^((l>>2)&3)  [involution matches read side]
    const int srow = l >> 2;
    const int scg = (l & 3) ^ (srow & 3);
    const u16* aSt = A + (size_t)(tileM + w * 16 + srow) * K + scg * 8;
    const u16* bSt = Bt + (size_t)(tileN + w * 16 + srow) * K + scg * 8;

    f32x4 acc[4][8] = {};

    // stage one ks-half of K-tile tt into buf nb: 4 gld16 (A h0, A h1, B h0, B h1)
    auto stageAB = [&](int ks, int tt, int nb) {
        const size_t ko = (size_t)(ks * 32 + tt * 64);
        gld16(aSt + ko, &As[nb][ks][(w * 16) * 32]);
        gld16(aSt + (size_t)128 * K + ko, &As[nb][ks][(128 + w * 16) * 32]);
        gld16(bSt + ko, &Bs[nb][ks][(w * 16) * 32]);
        gld16(bSt + (size_t)128 * K + ko, &Bs[nb][ks][(128 + w * 16) * 32]);
    };

    // one phase: sync, read 12 frags, stage next tile's same-ks half, 32 MFMA
    auto phase = [&](int ks, int buf, int tp) {
        asm volatile("s_waitcnt vmcnt(4)" ::: "memory");
        __builtin_amdgcn_s_barrier();
        asm volatile("" ::: "memory");  // no mem op crosses the sync point
        bf16x8 aR[4], bR[8];
#pragma unroll
        for (int i = 0; i < 4; ++i) {
            const int r = mw * 64 + i * 16 + mrow;
            aR[i] = *(const bf16x8*)&As[buf][ks][r * 32 + rco];
        }
#pragma unroll
        for (int j = 0; j < 8; ++j) {
            const int r = nw * 128 + j * 16 + mrow;
            bR[j] = *(const bf16x8*)&Bs[buf][ks][r * 32 + rco];
        }
        stageAB(ks, tp, buf ^ 1);
        __builtin_amdgcn_s_setprio(1);
#pragma unroll
        for (int i = 0; i < 4; ++i)
#pragma unroll
            for (int j = 0; j < 8; ++j)
                acc[i][j] = mfma16(aR[i], bR[j], acc[i][j]);
        __builtin_amdgcn_s_setprio(0);
    };

    // prologue: both ks-halves of tile 0 into buf 0 (fence keeps issue order
    // ks0-group before ks1-group so counted retirement stays exact)
    stageAB(0, 0, 0);
    asm volatile("" ::: "memory");
    stageAB(1, 0, 0);

    const int NT = K >> 6;
    for (int t = 0; t < NT; ++t) {
        const int buf = t & 1;
        const int tp = (t + 1 < NT) ? t + 1 : t;  // last tile: clamped dummy re-stage
        phase(0, buf, tp);
        phase(1, buf, tp);
    }
    asm volatile("s_waitcnt vmcnt(0)" ::: "memory");  // drain dangling dummy stages

    // epilogue. C/D layout: row=(l>>4)*4+r, col=l&15 [m89/m91].
    // tileN granularity 256 => whole block uniformly Q (<1024), K (<2048) or V.
    const int rbase = (l >> 4) * 4;
#pragma unroll
    for (int i = 0; i < 4; ++i) {
#pragma unroll
        for (int j = 0; j < 8; ++j) {
            const int gm0 = tileM + mw * 64 + i * 16 + rbase;
            const int gn = tileN + nw * 128 + j * 16 + (l & 15);
            const float bv_ = bias[gn];
            const f32x4 a = acc[i][j];
            if (tileN < 2048) {
                // fold softmax scale * log2e into Q
                const float qs = (tileN < 1024) ? 0.125f * 1.4426950408889634f : 1.0f;
#pragma unroll
                for (int r = 0; r < 4; ++r)
                    qkout[(size_t)(gm0 + r) * 2048 + gn] = f2b((a[r] + bv_) * qs);
            } else {
                const int b = gm0 >> 11, s0 = gm0 & 2047;
                const int gn2 = gn - 2048;
                const int h = gn2 >> 6, dh = gn2 & 63;
                ushort4 u;
                u.x = f2b(a[0] + bv_); u.y = f2b(a[1] + bv_);
                u.z = f2b(a[2] + bv_); u.w = f2b(a[3] + bv_);
                *(ushort4*)&vtout[((size_t)((b * 16 + h) * 64 + dh)) * 2048 + s0] = u;
            }
        }
    }
}

// ---------------------------------------------------------------- GEMM (old 128^2, MODE 1 only)
// C(M,N) = A(M,K) @ Bt(N,K)^T + bias. 128x128 tile, BK=32, 256 thr = 4 waves.
template <int MODE>
__global__ __launch_bounds__(256, 2) void gemm_bt(const u16* __restrict__ A,
                                                  const u16* __restrict__ Bt,
                                                  const float* __restrict__ bias,
                                                  void* __restrict__ Cout,
                                                  void* __restrict__ Cout2,
                                                  int M, int N, int K, int ldc) {
    const int tid = threadIdx.x;
    const int l = tid & 63;
    const int w = tid >> 6;
    const int tileM = blockIdx.x * 128;
    const int tileN = blockIdx.y * 128;

    __shared__ u16 As[2][128 * 32];  // [buf][row][k] stride 32
    __shared__ u16 Bs[2][128 * 32];

    const int srow = l >> 2;
    const int schunk = l & 3;
    const int mrow = l & 15;
    const int g8 = (l >> 4) * 8;
    const int waveM = (w & 1) * 64;
    const int waveN = (w >> 1) * 64;

    const u16* a0 = A + (size_t)(tileM + w * 32 + srow) * K + schunk * 8;
    const u16* a1 = A + (size_t)(tileM + w * 32 + 16 + srow) * K + schunk * 8;
    const u16* b0 = Bt + (size_t)(tileN + w * 32 + srow) * K + schunk * 8;
    const u16* b1 = Bt + (size_t)(tileN + w * 32 + 16 + srow) * K + schunk * 8;

    f32x4 acc[4][4] = {};

    gld16(a0, &As[0][(w * 2) * 512]);
    gld16(a1, &As[0][(w * 2 + 1) * 512]);
    gld16(b0, &Bs[0][(w * 2) * 512]);
    gld16(b1, &Bs[0][(w * 2 + 1) * 512]);
    __syncthreads();

    for (int k0 = 0; k0 < K; k0 += 32) {
        const int cur = (k0 >> 5) & 1;
        if (k0 + 32 < K) {
            const int nb = cur ^ 1;
            gld16(a0 + k0 + 32, &As[nb][(w * 2) * 512]);
            gld16(a1 + k0 + 32, &As[nb][(w * 2 + 1) * 512]);
            gld16(b0 + k0 + 32, &Bs[nb][(w * 2) * 512]);
            gld16(b1 + k0 + 32, &Bs[nb][(w * 2 + 1) * 512]);
        }

        bf16x8 af[4], bf[4];
        for (int im = 0; im < 4; ++im)
            af[im] = *(const bf16x8*)&As[cur][(waveM + im * 16 + mrow) * 32 + g8];
        for (int in = 0; in < 4; ++in)
            bf[in] = *(const bf16x8*)&Bs[cur][(waveN + in * 16 + mrow) * 32 + g8];
        for (int im = 0; im < 4; ++im)
            for (int in = 0; in < 4; ++in)
                acc[im][in] = mfma16(af[im], bf[in], acc[im][in]);
        __syncthreads();
    }

    const int rbase = (l >> 4) * 4;
    for (int im = 0; im < 4; ++im) {
        for (int in = 0; in < 4; ++in) {
            const int gm0 = tileM + waveM + im * 16 + rbase;
            const int gn = tileN + waveN + in * 16 + (l & 15);
            const float bv_ = bias[gn];
            if (MODE == 1) {
                float* out = (float*)Cout;
                for (int r = 0; r < 4; ++r)
                    out[(size_t)(gm0 + r) * ldc + gn] = acc[im][in][r] + bv_;
            } else if (tileN < 2048) {
                const float qs = (tileN < 1024) ? 0.125f * 1.4426950408889634f : 1.0f;
                u16* out = (u16*)Cout;
                for (int r = 0; r < 4; ++r)
                    out[(size_t)(gm0 + r) * 2048 + gn] = f2b((acc[im][in][r] + bv_) * qs);
            } else {
                u16* out = (u16*)Cout2;
                const int b = gm0 >> 11, s0 = gm0 & 2047;
                const int gn2 = gn - 2048;
                const int h = gn2 >> 6, dh = gn2 & 63;
                ushort4 u;
                u.x = f2b(acc[im][in][0] + bv_);
                u.y = f2b(acc[im][in][1] + bv_);
                u.z = f2b(acc[im][in][2] + bv_);
                u.w = f2b(acc[im][in][3] + bv_);
                *(ushort4*)&out[((size_t)((b * 16 + h) * 64 + dh)) * 2048 + s0] = u;
            }
        }
    }
}

// ---------------------------------------------------------------- flash attention
// R11 winner, unchanged: 256 thr = 4 waves, 128 queries/block, ONE barrier/round,
// K/V staged by global_load_lds DMA into double-buffered XOR-swizzled LDS tiles,
// max-free softmax with epilogue-only denominator reduction.
__global__ __launch_bounds__(256, 2) void attn_kernel(const u16* __restrict__ qk,
                                                      const u16* __restrict__ vt,
                                                      u16* __restrict__ attn) {
    const int bh = blockIdx.x;
    const int qt = 15 - (int)blockIdx.y;  // big q-tiles launch first
    const int b = bh >> 4, h = bh & 15;
    const int q0 = qt * 128;
    const int tid = threadIdx.x, l = tid & 63, w = tid >> 6;
    const int q = l & 15;   // query column within group
    const int g = l >> 4;   // k-group
    const int g8 = g * 8;

    __shared__ u16 Ks[2][64 * 64];  // [buf][key][dh]   XOR-swizzled chunks
    __shared__ u16 Vs[2][64 * 64];  // [buf][dh][key]   XOR-swizzled chunks
    __shared__ u16 Ps[128 * 72];    // Q staging, then per-wave P slabs [query][key]

    const int sr8 = l >> 3;
    const int gc = (l & 7) ^ sr8;
    const u16* kgl = qk + (size_t)(b * 2048 + w * 16 + sr8) * 2048 + 1024 + h * 64 + gc * 8;
    const u16* vgl = vt + (size_t)(bh * 64 + w * 16 + sr8) * 2048 + gc * 8;

    for (int i = 0; i < 4; ++i) {
        const int idx = i * 256 + tid;
        const int row = idx >> 3, ch = idx & 7;
        *(uint4*)&Ps[row * 72 + ch * 8] =
            *(const uint4*)&qk[(size_t)(b * 2048 + q0 + row) * 2048 + h * 64 + ch * 8];
    }
    for (int j = 0; j < 2; ++j) {
        gld16(kgl + (size_t)(j * 8) * 2048, &Ks[0][(w * 16 + j * 8) * 64]);
        gld16(vgl + (size_t)(j * 8) * 2048, &Vs[0][(w * 16 + j * 8) * 64]);
    }
    __syncthreads();

    bf16x8 qb[2][2];
    for (int c = 0; c < 2; ++c) {
        qb[c][0] = *(const bf16x8*)&Ps[(w * 32 + c * 16 + q) * 72 + g8];
        qb[c][1] = *(const bf16x8*)&Ps[(w * 32 + c * 16 + q) * 72 + 32 + g8];
    }

    const int cl0 = ((g) ^ (q & 7)) * 8;
    const int cl1 = ((4 + g) ^ (q & 7)) * 8;

    float li[2] = {0.f, 0.f};
    f32x4 o[2][4] = {};
    const int tmax = 2 * qt + 1;
    const int tdiag = (q0 + w * 32 + 31) >> 6;

    for (int t = 0; t <= tmax; ++t) {
        const int tp = (t < tmax) ? t + 1 : tmax;
        const int nb = (t + 1) & 1;
        for (int j = 0; j < 2; ++j) {
            gld16(kgl + (size_t)(tp * 64 + j * 8) * 2048, &Ks[nb][(w * 16 + j * 8) * 64]);
            gld16(vgl + (size_t)(j * 8) * 2048 + tp * 64, &Vs[nb][(w * 16 + j * 8) * 64]);
        }

        if (t <= tdiag) {
            const int cb0 = t & 1;
            const int kv0 = t * 64;
            const u16* ks = &Ks[cb0][0];
            const u16* vs = &Vs[cb0][0];

            f32x4 st[2][4] = {};
            for (int cb = 0; cb < 4; ++cb) {
                bf16x8 ka0 = *(const bf16x8*)&ks[(cb * 16 + q) * 64 + cl0];
                bf16x8 ka1 = *(const bf16x8*)&ks[(cb * 16 + q) * 64 + cl1];
                st[0][cb] = mfma16(ka0, qb[0][0], st[0][cb]);
                st[1][cb] = mfma16(ka0, qb[1][0], st[1][cb]);
                st[0][cb] = mfma16(ka1, qb[0][1], st[0][cb]);
                st[1][cb] = mfma16(ka1, qb[1][1], st[1][cb]);
            }
            for (int c = 0; c < 2; ++c) {
                if (t == tdiag) {
                    const int qg = q0 + w * 32 + c * 16 + q;
                    for (int cb = 0; cb < 4; ++cb)
                        for (int r = 0; r < 4; ++r) {
                            const int key = kv0 + cb * 16 + g * 4 + r;
                            if (key > qg) st[c][cb][r] = -1e30f;
                        }
                }
                float ps = 0.f;
                for (int cb = 0; cb < 4; ++cb)
                    for (int r = 0; r < 4; ++r) {
                        const float p = __builtin_amdgcn_exp2f(st[c][cb][r]);
                        st[c][cb][r] = p;
                        ps += p;
                    }
                li[c] += ps;
                for (int cb = 0; cb < 4; ++cb) {
                    ushort4 u;
                    u.x = f2b(st[c][cb][0]); u.y = f2b(st[c][cb][1]);
                    u.z = f2b(st[c][cb][2]); u.w = f2b(st[c][cb][3]);
                    *(ushort4*)&Ps[(w * 32 + c * 16 + q) * 72 + cb * 16 + g * 4] = u;
                }
            }
            __builtin_amdgcn_s_waitcnt(0xC07F);  // lgkmcnt(0)
            for (int cb = 0; cb < 4; ++cb) {
                bf16x8 va0 = *(const bf16x8*)&vs[(cb * 16 + q) * 64 + cl0];
                bf16x8 va1 = *(const bf16x8*)&vs[(cb * 16 + q) * 64 + cl1];
                bf16x8 pb00 = *(const bf16x8*)&Ps[(w * 32 + q) * 72 + g8];
                bf16x8 pb01 = *(const bf16x8*)&Ps[(w * 32 + q) * 72 + 32 + g8];
                bf16x8 pb10 = *(const bf16x8*)&Ps[(w * 32 + 16 + q) * 72 + g8];
                bf16x8 pb11 = *(const bf16x8*)&Ps[(w * 32 + 16 + q) * 72 + 32 + g8];
                o[0][cb] = mfma16(va0, pb00, o[0][cb]);
                o[1][cb] = mfma16(va0, pb10, o[1][cb]);
                o[0][cb] = mfma16(va1, pb01, o[0][cb]);
                o[1][cb] = mfma16(va1, pb11, o[1][cb]);
            }
        }
        __syncthreads();
    }

    for (int c = 0; c < 2; ++c) {
        float ps = li[c];
        ps += __shfl_xor(ps, 16);
        ps += __shfl_xor(ps, 32);
        const float inv = 1.0f / ps;
        const size_t tok = (size_t)(b * 2048 + q0 + w * 32 + c * 16 + q);
        for (int cb = 0; cb < 4; ++cb) {
            ushort4 u;
            u.x = f2b(o[c][cb][0] * inv); u.y = f2b(o[c][cb][1] * inv);
            u.z = f2b(o[c][cb][2] * inv); u.w = f2b(o[c][cb][3] * inv);
            *(ushort4*)&attn[tok * 1024 + h * 64 + cb * 16 + g * 4] = u;
        }
    }
}

// ---------------------------------------------------------------- launch
extern "C" void kernel_launch(void* const* d_in, const int* in_sizes, int n_in,
                              void* d_out, int out_size, void* d_ws, size_t ws_size,
                              hipStream_t stream) {
    const float* x  = (const float*)d_in[0];
    const float* Wq = (const float*)d_in[1];
    const float* bq = (const float*)d_in[2];
    const float* Wk = (const float*)d_in[3];
    const float* bk = (const float*)d_in[4];
    const float* Wv = (const float*)d_in[5];
    const float* bv = (const float*)d_in[6];
    const float* Wo = (const float*)d_in[7];
    const float* bo = (const float*)d_in[8];
    float* out = (float*)d_out;

    char* ws = (char*)d_ws;
    size_t off = 0;
    auto alloc = [&](size_t bytes) -> void* {
        void* p = ws + off;
        off += (bytes + 255) & ~(size_t)255;
        return p;
    };
    u16*   xb    = (u16*)alloc(8192ull * 1024 * 2);   // x bf16
    u16*   wqkvt = (u16*)alloc(3072ull * 1024 * 2);   // [Wq|Wk|Wv]^T (N,K)
    u16*   wot   = (u16*)alloc(1024ull * 1024 * 2);   // Wo^T
    float* bqkv  = (float*)alloc(3072ull * 4);
    u16*   qk    = (u16*)alloc(8192ull * 2048 * 2);   // [q|k] (token, 2048)
    u16*   vt    = (u16*)alloc(8192ull * 1024 * 2);   // V^T (B,H,Dh,S)
    u16*   attn  = (u16*)alloc(8192ull * 1024 * 2);   // attention out (token, D)

    convert_x<<<8192, 256, 0, stream>>>(x, xb, 8192 * 1024 / 4);
    transpose_w<<<dim3(32, 32, 4), dim3(32, 8), 0, stream>>>(Wq, Wk, Wv, Wo, wqkvt, wot);
    pack_bqkv<<<12, 256, 0, stream>>>(bq, bk, bv, bqkv);
    gemm256<<<dim3(32, 12), 512, 0, stream>>>(xb, wqkvt, bqkv, qk, vt, 1024);
    attn_kernel<<<dim3(64, 16), 256, 0, stream>>>(qk, vt, attn);
    gemm_bt<1><<<dim3(64, 8), 256, 0, stream>>>(attn, wot, bo, out, nullptr, 8192, 1024, 1024, 1024);
}

// Round 3
// 254.241 us; speedup vs baseline: 1.0539x; 1.0152x over previous
//
#include <hip/hip_runtime.h>
#include <hip/hip_bf16.h>

// CausalSelfAttention: B=4, S=2048, D=1024, H=16, Dh=64. fp32 in/out, bf16 MFMA compute.
//
// Pipeline (all on `stream`):
//   1. convert_x: x fp32 -> bf16 (8192x1024)
//   2. transpose_w: Wq|Wk|Wv -> wqkvt (3072x1024 bf16, N-major), Wo -> wot
//   3. pack_bqkv: [bq|bk|bv] -> fp32 (3072)
//   4. gemm256 v3: qkv = xb @ [Wq|Wk|Wv] + b -> qk bf16 (Q pre-scaled) + vt scatter.
//      R14: same two-phase ks-split schedule as R13 (vmcnt(4) counted, no
//      sched_barrier pinning), but CORRECTED swizzle sigma_r(c) = c ^ ((r>>1)&3).
//      R13 post-mortem: c ^ (r&3) correlated the XOR with row parity -> only 4/8
//      bank-groups covered -> 4-way conflict (4.7M counted). New mapping covers
//      all 8 bank-groups per 8 lanes -> conflict-free at any HW phasing.
//   5. attn: flash attention (R11 winner, unchanged)
//   6. gemm_bt<1>: out = attn @ Wo + bo -> fp32 d_out (old 128^2 kernel, unchanged)

typedef __bf16 bf16x8 __attribute__((ext_vector_type(8)));
typedef float f32x4 __attribute__((ext_vector_type(4)));
typedef unsigned short u16;

__device__ __forceinline__ u16 f2b(float f) {
    __hip_bfloat16 h = __float2bfloat16(f);
    return __builtin_bit_cast(unsigned short, h);
}

__device__ __forceinline__ f32x4 mfma16(bf16x8 a, bf16x8 b, f32x4 c) {
    return __builtin_amdgcn_mfma_f32_16x16x32_bf16(a, b, c, 0, 0, 0);
}

typedef const __attribute__((address_space(1))) unsigned int* gas1_t;
typedef __attribute__((address_space(3))) unsigned int* las3_t;
// Async global->LDS, 16B/lane. LDS dest = wave-uniform base + lane*16 (m104/m108).
__device__ __forceinline__ void gld16(const void* g, void* l) {
    __builtin_amdgcn_global_load_lds((gas1_t)g, (las3_t)l, 16, 0, 0);
}

// ---------------------------------------------------------------- conversions
__global__ __launch_bounds__(256) void convert_x(const float* __restrict__ x,
                                                 u16* __restrict__ xb, int n4) {
    int i = blockIdx.x * 256 + threadIdx.x;
    if (i < n4) {
        float4 v = ((const float4*)x)[i];
        ushort4 u;
        u.x = f2b(v.x); u.y = f2b(v.y); u.z = f2b(v.z); u.w = f2b(v.w);
        ((ushort4*)xb)[i] = u;
    }
}

// W (K=1024 rows, N=1024 cols) fp32 -> Wt (N,K) bf16. z selects matrix.
__global__ __launch_bounds__(256) void transpose_w(const float* __restrict__ Wq,
                                                   const float* __restrict__ Wk,
                                                   const float* __restrict__ Wv,
                                                   const float* __restrict__ Wo,
                                                   u16* __restrict__ wqkvt,
                                                   u16* __restrict__ wot) {
    const int z = blockIdx.z;
    const float* src = (z == 0) ? Wq : (z == 1) ? Wk : (z == 2) ? Wv : Wo;
    u16* dst = (z == 3) ? wot : (wqkvt + (size_t)z * 1024 * 1024);
    __shared__ float tile[32][33];
    const int tx = threadIdx.x, ty = threadIdx.y;  // block (32,8)
    const int nbase = blockIdx.x * 32, kbase = blockIdx.y * 32;
    for (int j = 0; j < 4; ++j)
        tile[ty + j * 8][tx] = src[(size_t)(kbase + ty + j * 8) * 1024 + nbase + tx];
    __syncthreads();
    for (int j = 0; j < 4; ++j)
        dst[(size_t)(nbase + ty + j * 8) * 1024 + kbase + tx] = f2b(tile[tx][ty + j * 8]);
}

__global__ __launch_bounds__(256) void pack_bqkv(const float* __restrict__ bq,
                                                 const float* __restrict__ bk,
                                                 const float* __restrict__ bv,
                                                 float* __restrict__ bqkv) {
    int i = blockIdx.x * 256 + threadIdx.x;  // 3072 total
    bqkv[i] = (i < 1024) ? bq[i] : (i < 2048) ? bk[i - 1024] : bv[i - 2048];
}

// ---------------------------------------------------------------- GEMM 256^2 v3
// C(M,N) = A(M,K) @ Bt(N,K)^T + bias, QKV epilogue. BM=BN=256, BK=64, 512 thr = 8 waves.
// Waves 4M x 2N: wave = 64 rows x 128 cols; acc[4][8] f32x4 (128 AGPR).
// LDS 128 KiB: As/Bs[2 dbuf][2 ks][256 rows][32 u16]; row = 64B = 4 x 16B chunks.
// Swizzle (R14 fix): LDS[row][c] holds global chunk c ^ ((row>>1)&3).
//   Bank-group of a frag read = 16*(r&1) + 4*(g ^ ((r>>1)&3)); over 8 consecutive
//   frag rows the (parity, xor) pairs enumerate all 8 bank-groups once ->
//   conflict-free (R13's c^(r&3) tied xor to parity: 4-way, 4.7M counted).
// Read offset per-lane constant: ((l>>4) ^ ((l>>1)&3))*16B.
// Stage: lane covers slab row l>>2, LDS chunk l&3, global chunk (l&3)^((l>>3)&3)
//   (coalesced 64B per 4-lane row group; slab bases %16==0 keep sigma consistent).
// vmcnt protocol (per wave, 4 loads/phase): vmcnt(4) at phase top retires exactly
// the 4 loads this phase reads; slack = 2 phases > HBM latency. Never 0 in-loop.
__global__ __launch_bounds__(512, 2) void gemm256(const u16* __restrict__ A,
                                                  const u16* __restrict__ Bt,
                                                  const float* __restrict__ bias,
                                                  u16* __restrict__ qkout,
                                                  u16* __restrict__ vtout,
                                                  int K) {
    const int tid = threadIdx.x;
    const int l = tid & 63;
    const int w = tid >> 6;   // 0..7
    const int mw = w >> 1;    // 0..3: wave rows = mw*64..mw*64+63
    const int nw = w & 1;     // 0..1: wave cols = nw*128..nw*128+127
    const int mrow = l & 15;
    const int tileM = blockIdx.x * 256;
    const int tileN = blockIdx.y * 256;

    __shared__ u16 As[2][2][256 * 32];  // [buf][ks][row*32+col]
    __shared__ u16 Bs[2][2][256 * 32];

    // read-side swizzled chunk offset (u16 units): chunk = (l>>4) ^ ((l>>1)&3)
    // (valid for all frag rows r = 16*base + mrow since (r>>1)&3 == (mrow>>1)&3)
    const int rco = ((l >> 4) ^ ((l >> 1) & 3)) * 8;

    // stage-side: lane covers row (l>>2) of a 16-row slab, LDS chunk l&3,
    // global chunk (l&3)^((l>>3)&3)  [involution matches read side]
    const int srow = l >> 2;
    const int scg = (l & 3) ^ ((l >> 3) & 3);
    const u16* aSt = A + (size_t)(tileM + w * 16 + srow) * K + scg * 8;
    const u16* bSt = Bt + (size_t)(tileN + w * 16 + srow) * K + scg * 8;

    f32x4 acc[4][8] = {};

    // stage one ks-half of K-tile tt into buf nb: 4 gld16 (A h0, A h1, B h0, B h1)
    auto stageAB = [&](int ks, int tt, int nb) {
        const size_t ko = (size_t)(ks * 32 + tt * 64);
        gld16(aSt + ko, &As[nb][ks][(w * 16) * 32]);
        gld16(aSt + (size_t)128 * K + ko, &As[nb][ks][(128 + w * 16) * 32]);
        gld16(bSt + ko, &Bs[nb][ks][(w * 16) * 32]);
        gld16(bSt + (size_t)128 * K + ko, &Bs[nb][ks][(128 + w * 16) * 32]);
    };

    // one phase: sync, read 12 frags, stage next tile's same-ks half, 32 MFMA
    auto phase = [&](int ks, int buf, int tp) {
        asm volatile("s_waitcnt vmcnt(4)" ::: "memory");
        __builtin_amdgcn_s_barrier();
        asm volatile("" ::: "memory");  // no mem op crosses the sync point
        bf16x8 aR[4], bR[8];
#pragma unroll
        for (int i = 0; i < 4; ++i) {
            const int r = mw * 64 + i * 16 + mrow;
            aR[i] = *(const bf16x8*)&As[buf][ks][r * 32 + rco];
        }
#pragma unroll
        for (int j = 0; j < 8; ++j) {
            const int r = nw * 128 + j * 16 + mrow;
            bR[j] = *(const bf16x8*)&Bs[buf][ks][r * 32 + rco];
        }
        stageAB(ks, tp, buf ^ 1);
        __builtin_amdgcn_s_setprio(1);
#pragma unroll
        for (int i = 0; i < 4; ++i)
#pragma unroll
            for (int j = 0; j < 8; ++j)
                acc[i][j] = mfma16(aR[i], bR[j], acc[i][j]);
        __builtin_amdgcn_s_setprio(0);
    };

    // prologue: both ks-halves of tile 0 into buf 0 (fence keeps issue order
    // ks0-group before ks1-group so counted retirement stays exact)
    stageAB(0, 0, 0);
    asm volatile("" ::: "memory");
    stageAB(1, 0, 0);

    const int NT = K >> 6;
    for (int t = 0; t < NT; ++t) {
        const int buf = t & 1;
        const int tp = (t + 1 < NT) ? t + 1 : t;  // last tile: clamped dummy re-stage
        phase(0, buf, tp);
        phase(1, buf, tp);
    }
    asm volatile("s_waitcnt vmcnt(0)" ::: "memory");  // drain dangling dummy stages

    // epilogue. C/D layout: row=(l>>4)*4+r, col=l&15 [m89/m91].
    // tileN granularity 256 => whole block uniformly Q (<1024), K (<2048) or V.
    const int rbase = (l >> 4) * 4;
#pragma unroll
    for (int i = 0; i < 4; ++i) {
#pragma unroll
        for (int j = 0; j < 8; ++j) {
            const int gm0 = tileM + mw * 64 + i * 16 + rbase;
            const int gn = tileN + nw * 128 + j * 16 + (l & 15);
            const float bv_ = bias[gn];
            const f32x4 a = acc[i][j];
            if (tileN < 2048) {
                // fold softmax scale * log2e into Q
                const float qs = (tileN < 1024) ? 0.125f * 1.4426950408889634f : 1.0f;
#pragma unroll
                for (int r = 0; r < 4; ++r)
                    qkout[(size_t)(gm0 + r) * 2048 + gn] = f2b((a[r] + bv_) * qs);
            } else {
                const int b = gm0 >> 11, s0 = gm0 & 2047;
                const int gn2 = gn - 2048;
                const int h = gn2 >> 6, dh = gn2 & 63;
                ushort4 u;
                u.x = f2b(a[0] + bv_); u.y = f2b(a[1] + bv_);
                u.z = f2b(a[2] + bv_); u.w = f2b(a[3] + bv_);
                *(ushort4*)&vtout[((size_t)((b * 16 + h) * 64 + dh)) * 2048 + s0] = u;
            }
        }
    }
}

// ---------------------------------------------------------------- GEMM (old 128^2, MODE 1 only)
// C(M,N) = A(M,K) @ Bt(N,K)^T + bias. 128x128 tile, BK=32, 256 thr = 4 waves.
template <int MODE>
__global__ __launch_bounds__(256, 2) void gemm_bt(const u16* __restrict__ A,
                                                  const u16* __restrict__ Bt,
                                                  const float* __restrict__ bias,
                                                  void* __restrict__ Cout,
                                                  void* __restrict__ Cout2,
                                                  int M, int N, int K, int ldc) {
    const int tid = threadIdx.x;
    const int l = tid & 63;
    const int w = tid >> 6;
    const int tileM = blockIdx.x * 128;
    const int tileN = blockIdx.y * 128;

    __shared__ u16 As[2][128 * 32];  // [buf][row][k] stride 32
    __shared__ u16 Bs[2][128 * 32];

    const int srow = l >> 2;
    const int schunk = l & 3;
    const int mrow = l & 15;
    const int g8 = (l >> 4) * 8;
    const int waveM = (w & 1) * 64;
    const int waveN = (w >> 1) * 64;

    const u16* a0 = A + (size_t)(tileM + w * 32 + srow) * K + schunk * 8;
    const u16* a1 = A + (size_t)(tileM + w * 32 + 16 + srow) * K + schunk * 8;
    const u16* b0 = Bt + (size_t)(tileN + w * 32 + srow) * K + schunk * 8;
    const u16* b1 = Bt + (size_t)(tileN + w * 32 + 16 + srow) * K + schunk * 8;

    f32x4 acc[4][4] = {};

    gld16(a0, &As[0][(w * 2) * 512]);
    gld16(a1, &As[0][(w * 2 + 1) * 512]);
    gld16(b0, &Bs[0][(w * 2) * 512]);
    gld16(b1, &Bs[0][(w * 2 + 1) * 512]);
    __syncthreads();

    for (int k0 = 0; k0 < K; k0 += 32) {
        const int cur = (k0 >> 5) & 1;
        if (k0 + 32 < K) {
            const int nb = cur ^ 1;
            gld16(a0 + k0 + 32, &As[nb][(w * 2) * 512]);
            gld16(a1 + k0 + 32, &As[nb][(w * 2 + 1) * 512]);
            gld16(b0 + k0 + 32, &Bs[nb][(w * 2) * 512]);
            gld16(b1 + k0 + 32, &Bs[nb][(w * 2 + 1) * 512]);
        }

        bf16x8 af[4], bf[4];
        for (int im = 0; im < 4; ++im)
            af[im] = *(const bf16x8*)&As[cur][(waveM + im * 16 + mrow) * 32 + g8];
        for (int in = 0; in < 4; ++in)
            bf[in] = *(const bf16x8*)&Bs[cur][(waveN + in * 16 + mrow) * 32 + g8];
        for (int im = 0; im < 4; ++im)
            for (int in = 0; in < 4; ++in)
                acc[im][in] = mfma16(af[im], bf[in], acc[im][in]);
        __syncthreads();
    }

    const int rbase = (l >> 4) * 4;
    for (int im = 0; im < 4; ++im) {
        for (int in = 0; in < 4; ++in) {
            const int gm0 = tileM + waveM + im * 16 + rbase;
            const int gn = tileN + waveN + in * 16 + (l & 15);
            const float bv_ = bias[gn];
            if (MODE == 1) {
                float* out = (float*)Cout;
                for (int r = 0; r < 4; ++r)
                    out[(size_t)(gm0 + r) * ldc + gn] = acc[im][in][r] + bv_;
            } else if (tileN < 2048) {
                const float qs = (tileN < 1024) ? 0.125f * 1.4426950408889634f : 1.0f;
                u16* out = (u16*)Cout;
                for (int r = 0; r < 4; ++r)
                    out[(size_t)(gm0 + r) * 2048 + gn] = f2b((acc[im][in][r] + bv_) * qs);
            } else {
                u16* out = (u16*)Cout2;
                const int b = gm0 >> 11, s0 = gm0 & 2047;
                const int gn2 = gn - 2048;
                const int h = gn2 >> 6, dh = gn2 & 63;
                ushort4 u;
                u.x = f2b(acc[im][in][0] + bv_);
                u.y = f2b(acc[im][in][1] + bv_);
                u.z = f2b(acc[im][in][2] + bv_);
                u.w = f2b(acc[im][in][3] + bv_);
                *(ushort4*)&out[((size_t)((b * 16 + h) * 64 + dh)) * 2048 + s0] = u;
            }
        }
    }
}

// ---------------------------------------------------------------- flash attention
// R11 winner, unchanged: 256 thr = 4 waves, 128 queries/block, ONE barrier/round,
// K/V staged by global_load_lds DMA into double-buffered XOR-swizzled LDS tiles,
// max-free softmax with epilogue-only denominator reduction.
__global__ __launch_bounds__(256, 2) void attn_kernel(const u16* __restrict__ qk,
                                                      const u16* __restrict__ vt,
                                                      u16* __restrict__ attn) {
    const int bh = blockIdx.x;
    const int qt = 15 - (int)blockIdx.y;  // big q-tiles launch first
    const int b = bh >> 4, h = bh & 15;
    const int q0 = qt * 128;
    const int tid = threadIdx.x, l = tid & 63, w = tid >> 6;
    const int q = l & 15;   // query column within group
    const int g = l >> 4;   // k-group
    const int g8 = g * 8;

    __shared__ u16 Ks[2][64 * 64];  // [buf][key][dh]   XOR-swizzled chunks
    __shared__ u16 Vs[2][64 * 64];  // [buf][dh][key]   XOR-swizzled chunks
    __shared__ u16 Ps[128 * 72];    // Q staging, then per-wave P slabs [query][key]

    const int sr8 = l >> 3;
    const int gc = (l & 7) ^ sr8;
    const u16* kgl = qk + (size_t)(b * 2048 + w * 16 + sr8) * 2048 + 1024 + h * 64 + gc * 8;
    const u16* vgl = vt + (size_t)(bh * 64 + w * 16 + sr8) * 2048 + gc * 8;

    for (int i = 0; i < 4; ++i) {
        const int idx = i * 256 + tid;
        const int row = idx >> 3, ch = idx & 7;
        *(uint4*)&Ps[row * 72 + ch * 8] =
            *(const uint4*)&qk[(size_t)(b * 2048 + q0 + row) * 2048 + h * 64 + ch * 8];
    }
    for (int j = 0; j < 2; ++j) {
        gld16(kgl + (size_t)(j * 8) * 2048, &Ks[0][(w * 16 + j * 8) * 64]);
        gld16(vgl + (size_t)(j * 8) * 2048, &Vs[0][(w * 16 + j * 8) * 64]);
    }
    __syncthreads();

    bf16x8 qb[2][2];
    for (int c = 0; c < 2; ++c) {
        qb[c][0] = *(const bf16x8*)&Ps[(w * 32 + c * 16 + q) * 72 + g8];
        qb[c][1] = *(const bf16x8*)&Ps[(w * 32 + c * 16 + q) * 72 + 32 + g8];
    }

    const int cl0 = ((g) ^ (q & 7)) * 8;
    const int cl1 = ((4 + g) ^ (q & 7)) * 8;

    float li[2] = {0.f, 0.f};
    f32x4 o[2][4] = {};
    const int tmax = 2 * qt + 1;
    const int tdiag = (q0 + w * 32 + 31) >> 6;

    for (int t = 0; t <= tmax; ++t) {
        const int tp = (t < tmax) ? t + 1 : tmax;
        const int nb = (t + 1) & 1;
        for (int j = 0; j < 2; ++j) {
            gld16(kgl + (size_t)(tp * 64 + j * 8) * 2048, &Ks[nb][(w * 16 + j * 8) * 64]);
            gld16(vgl + (size_t)(j * 8) * 2048 + tp * 64, &Vs[nb][(w * 16 + j * 8) * 64]);
        }

        if (t <= tdiag) {
            const int cb0 = t & 1;
            const int kv0 = t * 64;
            const u16* ks = &Ks[cb0][0];
            const u16* vs = &Vs[cb0][0];

            f32x4 st[2][4] = {};
            for (int cb = 0; cb < 4; ++cb) {
                bf16x8 ka0 = *(const bf16x8*)&ks[(cb * 16 + q) * 64 + cl0];
                bf16x8 ka1 = *(const bf16x8*)&ks[(cb * 16 + q) * 64 + cl1];
                st[0][cb] = mfma16(ka0, qb[0][0], st[0][cb]);
                st[1][cb] = mfma16(ka0, qb[1][0], st[1][cb]);
                st[0][cb] = mfma16(ka1, qb[0][1], st[0][cb]);
                st[1][cb] = mfma16(ka1, qb[1][1], st[1][cb]);
            }
            for (int c = 0; c < 2; ++c) {
                if (t == tdiag) {
                    const int qg = q0 + w * 32 + c * 16 + q;
                    for (int cb = 0; cb < 4; ++cb)
                        for (int r = 0; r < 4; ++r) {
                            const int key = kv0 + cb * 16 + g * 4 + r;
                            if (key > qg) st[c][cb][r] = -1e30f;
                        }
                }
                float ps = 0.f;
                for (int cb = 0; cb < 4; ++cb)
                    for (int r = 0; r < 4; ++r) {
                        const float p = __builtin_amdgcn_exp2f(st[c][cb][r]);
                        st[c][cb][r] = p;
                        ps += p;
                    }
                li[c] += ps;
                for (int cb = 0; cb < 4; ++cb) {
                    ushort4 u;
                    u.x = f2b(st[c][cb][0]); u.y = f2b(st[c][cb][1]);
                    u.z = f2b(st[c][cb][2]); u.w = f2b(st[c][cb][3]);
                    *(ushort4*)&Ps[(w * 32 + c * 16 + q) * 72 + cb * 16 + g * 4] = u;
                }
            }
            __builtin_amdgcn_s_waitcnt(0xC07F);  // lgkmcnt(0)
            for (int cb = 0; cb < 4; ++cb) {
                bf16x8 va0 = *(const bf16x8*)&vs[(cb * 16 + q) * 64 + cl0];
                bf16x8 va1 = *(const bf16x8*)&vs[(cb * 16 + q) * 64 + cl1];
                bf16x8 pb00 = *(const bf16x8*)&Ps[(w * 32 + q) * 72 + g8];
                bf16x8 pb01 = *(const bf16x8*)&Ps[(w * 32 + q) * 72 + 32 + g8];
                bf16x8 pb10 = *(const bf16x8*)&Ps[(w * 32 + 16 + q) * 72 + g8];
                bf16x8 pb11 = *(const bf16x8*)&Ps[(w * 32 + 16 + q) * 72 + 32 + g8];
                o[0][cb] = mfma16(va0, pb00, o[0][cb]);
                o[1][cb] = mfma16(va0, pb10, o[1][cb]);
                o[0][cb] = mfma16(va1, pb01, o[0][cb]);
                o[1][cb] = mfma16(va1, pb11, o[1][cb]);
            }
        }
        __syncthreads();
    }

    for (int c = 0; c < 2; ++c) {
        float ps = li[c];
        ps += __shfl_xor(ps, 16);
        ps += __shfl_xor(ps, 32);
        const float inv = 1.0f / ps;
        const size_t tok = (size_t)(b * 2048 + q0 + w * 32 + c * 16 + q);
        for (int cb = 0; cb < 4; ++cb) {
            ushort4 u;
            u.x = f2b(o[c][cb][0] * inv); u.y = f2b(o[c][cb][1] * inv);
            u.z = f2b(o[c][cb][2] * inv); u.w = f2b(o[c][cb][3] * inv);
            *(ushort4*)&attn[tok * 1024 + h * 64 + cb * 16 + g * 4] = u;
        }
    }
}

// ---------------------------------------------------------------- launch
extern "C" void kernel_launch(void* const* d_in, const int* in_sizes, int n_in,
                              void* d_out, int out_size, void* d_ws, size_t ws_size,
                              hipStream_t stream) {
    const float* x  = (const float*)d_in[0];
    const float* Wq = (const float*)d_in[1];
    const float* bq = (const float*)d_in[2];
    const float* Wk = (const float*)d_in[3];
    const float* bk = (const float*)d_in[4];
    const float* Wv = (const float*)d_in[5];
    const float* bv = (const float*)d_in[6];
    const float* Wo = (const float*)d_in[7];
    const float* bo = (const float*)d_in[8];
    float* out = (float*)d_out;

    char* ws = (char*)d_ws;
    size_t off = 0;
    auto alloc = [&](size_t bytes) -> void* {
        void* p = ws + off;
        off += (bytes + 255) & ~(size_t)255;
        return p;
    };
    u16*   xb    = (u16*)alloc(8192ull * 1024 * 2);   // x bf16
    u16*   wqkvt = (u16*)alloc(3072ull * 1024 * 2);   // [Wq|Wk|Wv]^T (N,K)
    u16*   wot   = (u16*)alloc(1024ull * 1024 * 2);   // Wo^T
    float* bqkv  = (float*)alloc(3072ull * 4);
    u16*   qk    = (u16*)alloc(8192ull * 2048 * 2);   // [q|k] (token, 2048)
    u16*   vt    = (u16*)alloc(8192ull * 1024 * 2);   // V^T (B,H,Dh,S)
    u16*   attn  = (u16*)alloc(8192ull * 1024 * 2);   // attention out (token, D)

    convert_x<<<8192, 256, 0, stream>>>(x, xb, 8192 * 1024 / 4);
    transpose_w<<<dim3(32, 32, 4), dim3(32, 8), 0, stream>>>(Wq, Wk, Wv, Wo, wqkvt, wot);
    pack_bqkv<<<12, 256, 0, stream>>>(bq, bk, bv, bqkv);
    gemm256<<<dim3(32, 12), 512, 0, stream>>>(xb, wqkvt, bqkv, qk, vt, 1024);
    attn_kernel<<<dim3(64, 16), 256, 0, stream>>>(qk, vt, attn);
    gemm_bt<1><<<dim3(64, 8), 256, 0, stream>>>(attn, wot, bo, out, nullptr, 8192, 1024, 1024, 1024);
}

// Round 4
// 244.666 us; speedup vs baseline: 1.0952x; 1.0391x over previous
//
#include <hip/hip_runtime.h>
#include <hip/hip_bf16.h>

// CausalSelfAttention: B=4, S=2048, D=1024, H=16, Dh=64. fp32 in/out, bf16 MFMA compute.
//
// Pipeline (all on `stream`):
//   1. convert_x: x fp32 -> bf16 (8192x1024)
//   2. transpose_w: Wq|Wk|Wv -> wqkvt (3072x1024 bf16, N-major), Wo -> wot
//   3. pack_bqkv: [bq|bk|bv] -> fp32 (3072)
//   4. gemm256 v4: qkv = xb @ [Wq|Wk|Wv] + b -> qk bf16 (Q pre-scaled) + vt scatter.
//      R15: ONE __syncthreads per K-tile (implicit vmcnt(0) is the only drain;
//      stages have 1-4 phases of slack). Inside the tile: 4 register-reuse quadrant
//      phases (16 MFMA each) with reads interleaved and NO explicit waits/barriers
//      -> per-wave compiler lgkmcnt lets the 8 waves skew so one wave's LDS drain
//      overlaps another's MFMA (R14 post-mortem: lockstep phases alternated the
//      LDS and MFMA pipes instead of overlapping them; conflicts were already 0).
//      Wave grid 2Mx4N (128x64/wave). LDS [2][256][64] chunk^=(row&7) swizzle.
//   5. attn: flash attention (R11 winner, unchanged)
//   6. gemm_bt<1>: out = attn @ Wo + bo -> fp32 d_out (old 128^2 kernel, unchanged)

typedef __bf16 bf16x8 __attribute__((ext_vector_type(8)));
typedef float f32x4 __attribute__((ext_vector_type(4)));
typedef unsigned short u16;

__device__ __forceinline__ u16 f2b(float f) {
    __hip_bfloat16 h = __float2bfloat16(f);
    return __builtin_bit_cast(unsigned short, h);
}

__device__ __forceinline__ f32x4 mfma16(bf16x8 a, bf16x8 b, f32x4 c) {
    return __builtin_amdgcn_mfma_f32_16x16x32_bf16(a, b, c, 0, 0, 0);
}

typedef const __attribute__((address_space(1))) unsigned int* gas1_t;
typedef __attribute__((address_space(3))) unsigned int* las3_t;
// Async global->LDS, 16B/lane. LDS dest = wave-uniform base + lane*16 (m104/m108).
__device__ __forceinline__ void gld16(const void* g, void* l) {
    __builtin_amdgcn_global_load_lds((gas1_t)g, (las3_t)l, 16, 0, 0);
}

// ---------------------------------------------------------------- conversions
__global__ __launch_bounds__(256) void convert_x(const float* __restrict__ x,
                                                 u16* __restrict__ xb, int n4) {
    int i = blockIdx.x * 256 + threadIdx.x;
    if (i < n4) {
        float4 v = ((const float4*)x)[i];
        ushort4 u;
        u.x = f2b(v.x); u.y = f2b(v.y); u.z = f2b(v.z); u.w = f2b(v.w);
        ((ushort4*)xb)[i] = u;
    }
}

// W (K=1024 rows, N=1024 cols) fp32 -> Wt (N,K) bf16. z selects matrix.
__global__ __launch_bounds__(256) void transpose_w(const float* __restrict__ Wq,
                                                   const float* __restrict__ Wk,
                                                   const float* __restrict__ Wv,
                                                   const float* __restrict__ Wo,
                                                   u16* __restrict__ wqkvt,
                                                   u16* __restrict__ wot) {
    const int z = blockIdx.z;
    const float* src = (z == 0) ? Wq : (z == 1) ? Wk : (z == 2) ? Wv : Wo;
    u16* dst = (z == 3) ? wot : (wqkvt + (size_t)z * 1024 * 1024);
    __shared__ float tile[32][33];
    const int tx = threadIdx.x, ty = threadIdx.y;  // block (32,8)
    const int nbase = blockIdx.x * 32, kbase = blockIdx.y * 32;
    for (int j = 0; j < 4; ++j)
        tile[ty + j * 8][tx] = src[(size_t)(kbase + ty + j * 8) * 1024 + nbase + tx];
    __syncthreads();
    for (int j = 0; j < 4; ++j)
        dst[(size_t)(nbase + ty + j * 8) * 1024 + kbase + tx] = f2b(tile[tx][ty + j * 8]);
}

__global__ __launch_bounds__(256) void pack_bqkv(const float* __restrict__ bq,
                                                 const float* __restrict__ bk,
                                                 const float* __restrict__ bv,
                                                 float* __restrict__ bqkv) {
    int i = blockIdx.x * 256 + threadIdx.x;  // 3072 total
    bqkv[i] = (i < 1024) ? bq[i] : (i < 2048) ? bk[i - 1024] : bv[i - 2048];
}

// ---------------------------------------------------------------- GEMM 256^2 v4
// C(M,N) = A(M,K) @ Bt(N,K)^T + bias, QKV epilogue. BM=BN=256, BK=64, 512 thr = 8 waves.
// Waves 2M x 4N: wave = 128 rows x 64 cols; acc[8][4] f32x4 (128 AGPR).
// LDS 128 KiB: As/Bs[2 dbuf][256 rows][64 u16]; row = 128B = 8 x 16B chunks.
// Swizzle: LDS[r][c] holds global chunk c ^ (r&7) (involution). A frag read:
//   lane l -> row base + (l&15), chunk (ks*4 + (l>>4)) ^ (l&7); the 8 chunk-columns
//   are each hit by exactly 8 of 64 lanes -> conflict-free.
// Stage unit = one 128-row half (A-h or B-h) x full BK: 16KB/block = 2 gld16/wave.
//   gld16 dest linear (8 rows x 128B); per-lane global src row +(l>>3),
//   chunk (l&7)^(l>>3) (pre-swizzled source, rule #21).
// Sync protocol: ONE __syncthreads per K-tile. Its implicit vmcnt(0) retires the
//   4 units of this tile, staged during the previous tile's phases with slack:
//   A-h0 4 phases, A-h1 3, B-h0 2, B-h1 1 (A = HBM-latency staged earliest;
//   B = L2-hot weights staged last). No other waits: compiler emits per-wave
//   counted lgkmcnt for ds_read->MFMA, waves skew freely within the tile.
__global__ __launch_bounds__(512, 2) void gemm256(const u16* __restrict__ A,
                                                  const u16* __restrict__ Bt,
                                                  const float* __restrict__ bias,
                                                  u16* __restrict__ qkout,
                                                  u16* __restrict__ vtout,
                                                  int K) {
    const int tid = threadIdx.x;
    const int l = tid & 63;
    const int w = tid >> 6;   // 0..7
    const int mw2 = w >> 2;   // 0..1: wave rows = mw2*128..+127
    const int nw4 = w & 3;    // 0..3: wave cols = nw4*64..+63
    const int tileM = blockIdx.x * 256;
    const int tileN = blockIdx.y * 256;

    __shared__ u16 As[2][256 * 64];  // [buf][row*64 + col], 128B rows
    __shared__ u16 Bs[2][256 * 64];

    // read-side swizzled chunk offsets (u16 units) per ks: ((ks*4+(l>>4)) ^ (l&7))*8
    const int co0 = (((l >> 4)) ^ (l & 7)) * 8;
    const int co1 = ((4 + (l >> 4)) ^ (l & 7)) * 8;
    const int mrow = l & 15;

    // stage-side per-lane global base: row offset (l>>3), chunk (l&7)^(l>>3)
    const int sro = l >> 3;
    const int scg = (l & 7) ^ sro;
    const u16* aSt = A + (size_t)(tileM + w * 16 + sro) * K + scg * 8;
    const u16* bSt = Bt + (size_t)(tileN + w * 16 + sro) * K + scg * 8;

    f32x4 acc[8][4] = {};
    bf16x8 aR[4][2];  // current m-half: 4 m-frags x 2 ks
    bf16x8 bR[4][2];  // both n-halves: 4 n-frags x 2 ks (held all tile)

    // stage one 128-row half (mat: 0=A, 1=B) of K-tile tt into buf nb
    auto stage = [&](int mat, int h, int tt, int nb) {
        const size_t go = (size_t)h * 128 * K + (size_t)tt * 64;
        u16* lb = (mat ? &Bs[nb][0] : &As[nb][0]) + (h * 128 + w * 16) * 64;
        const u16* gp = (mat ? bSt : aSt) + go;
        gld16(gp, lb);
        gld16(gp + (size_t)8 * K, lb + 8 * 64);
    };
    // load A m-half mh (4 frags x 2 ks) from buf
    auto loadA = [&](int mh, int buf) {
#pragma unroll
        for (int i = 0; i < 4; ++i) {
            const int r = mw2 * 128 + mh * 64 + i * 16 + mrow;
            aR[i][0] = *(const bf16x8*)&As[buf][r * 64 + co0];
            aR[i][1] = *(const bf16x8*)&As[buf][r * 64 + co1];
        }
    };
    // load B n-half nh (2 frags x 2 ks) into bR[nh*2..nh*2+1]
    auto loadB = [&](int nh, int buf) {
#pragma unroll
        for (int j = 0; j < 2; ++j) {
            const int r = nw4 * 64 + nh * 32 + j * 16 + mrow;
            bR[nh * 2 + j][0] = *(const bf16x8*)&Bs[buf][r * 64 + co0];
            bR[nh * 2 + j][1] = *(const bf16x8*)&Bs[buf][r * 64 + co1];
        }
    };
    // 16-MFMA cluster: m-frags [mi0..mi0+3] x n-frags [nj0..nj0+1] x 2 ks
    auto mm = [&](int mi0, int nj0) {
        __builtin_amdgcn_s_setprio(1);
#pragma unroll
        for (int ks = 0; ks < 2; ++ks)
#pragma unroll
            for (int i = 0; i < 4; ++i)
#pragma unroll
                for (int j = 0; j < 2; ++j)
                    acc[mi0 + i][nj0 + j] =
                        mfma16(aR[i][ks], bR[nj0 + j][ks], acc[mi0 + i][nj0 + j]);
        __builtin_amdgcn_s_setprio(0);
    };

    // prologue: all 4 units of tile 0 into buf 0
    stage(0, 0, 0, 0); stage(0, 1, 0, 0); stage(1, 0, 0, 0); stage(1, 1, 0, 0);

    const int NT = K >> 6;
    for (int t = 0; t < NT; ++t) {
        const int buf = t & 1, nb = buf ^ 1;
        const bool pf = (t + 1 < NT);
        __syncthreads();  // implicit vmcnt(0)+lgkmcnt(0): this tile's units resident

        // q0: (m-half 0, n-half 0)   reads 12, stage A-h0(t+1)
        loadA(0, buf);
        loadB(0, buf);
        if (pf) stage(0, 0, t + 1, nb);
        mm(0, 0);
        // q1: (m0, n1)               reads 4, stage A-h1(t+1)
        loadB(1, buf);
        if (pf) stage(0, 1, t + 1, nb);
        mm(0, 2);
        // q2: (m1, n1)               reads 8, stage B-h0(t+1)
        loadA(1, buf);
        if (pf) stage(1, 0, t + 1, nb);
        mm(4, 2);
        // q3: (m1, n0)               reads 0, stage B-h1(t+1)
        if (pf) stage(1, 1, t + 1, nb);
        mm(4, 0);
    }

    // epilogue. C/D layout: row=(l>>4)*4+r, col=l&15 [m89/m91].
    // tileN granularity 256 => whole block uniformly Q (<1024), K (<2048) or V.
    const int rbase = (l >> 4) * 4;
#pragma unroll
    for (int i = 0; i < 8; ++i) {
#pragma unroll
        for (int j = 0; j < 4; ++j) {
            const int gm0 = tileM + mw2 * 128 + i * 16 + rbase;
            const int gn = tileN + nw4 * 64 + j * 16 + (l & 15);
            const float bv_ = bias[gn];
            const f32x4 a = acc[i][j];
            if (tileN < 2048) {
                // fold softmax scale * log2e into Q
                const float qs = (tileN < 1024) ? 0.125f * 1.4426950408889634f : 1.0f;
#pragma unroll
                for (int r = 0; r < 4; ++r)
                    qkout[(size_t)(gm0 + r) * 2048 + gn] = f2b((a[r] + bv_) * qs);
            } else {
                const int b = gm0 >> 11, s0 = gm0 & 2047;
                const int gn2 = gn - 2048;
                const int h = gn2 >> 6, dh = gn2 & 63;
                ushort4 u;
                u.x = f2b(a[0] + bv_); u.y = f2b(a[1] + bv_);
                u.z = f2b(a[2] + bv_); u.w = f2b(a[3] + bv_);
                *(ushort4*)&vtout[((size_t)((b * 16 + h) * 64 + dh)) * 2048 + s0] = u;
            }
        }
    }
}

// ---------------------------------------------------------------- GEMM (old 128^2, MODE 1 only)
// C(M,N) = A(M,K) @ Bt(N,K)^T + bias. 128x128 tile, BK=32, 256 thr = 4 waves.
template <int MODE>
__global__ __launch_bounds__(256, 2) void gemm_bt(const u16* __restrict__ A,
                                                  const u16* __restrict__ Bt,
                                                  const float* __restrict__ bias,
                                                  void* __restrict__ Cout,
                                                  void* __restrict__ Cout2,
                                                  int M, int N, int K, int ldc) {
    const int tid = threadIdx.x;
    const int l = tid & 63;
    const int w = tid >> 6;
    const int tileM = blockIdx.x * 128;
    const int tileN = blockIdx.y * 128;

    __shared__ u16 As[2][128 * 32];  // [buf][row][k] stride 32
    __shared__ u16 Bs[2][128 * 32];

    const int srow = l >> 2;
    const int schunk = l & 3;
    const int mrow = l & 15;
    const int g8 = (l >> 4) * 8;
    const int waveM = (w & 1) * 64;
    const int waveN = (w >> 1) * 64;

    const u16* a0 = A + (size_t)(tileM + w * 32 + srow) * K + schunk * 8;
    const u16* a1 = A + (size_t)(tileM + w * 32 + 16 + srow) * K + schunk * 8;
    const u16* b0 = Bt + (size_t)(tileN + w * 32 + srow) * K + schunk * 8;
    const u16* b1 = Bt + (size_t)(tileN + w * 32 + 16 + srow) * K + schunk * 8;

    f32x4 acc[4][4] = {};

    gld16(a0, &As[0][(w * 2) * 512]);
    gld16(a1, &As[0][(w * 2 + 1) * 512]);
    gld16(b0, &Bs[0][(w * 2) * 512]);
    gld16(b1, &Bs[0][(w * 2 + 1) * 512]);
    __syncthreads();

    for (int k0 = 0; k0 < K; k0 += 32) {
        const int cur = (k0 >> 5) & 1;
        if (k0 + 32 < K) {
            const int nb = cur ^ 1;
            gld16(a0 + k0 + 32, &As[nb][(w * 2) * 512]);
            gld16(a1 + k0 + 32, &As[nb][(w * 2 + 1) * 512]);
            gld16(b0 + k0 + 32, &Bs[nb][(w * 2) * 512]);
            gld16(b1 + k0 + 32, &Bs[nb][(w * 2 + 1) * 512]);
        }

        bf16x8 af[4], bf[4];
        for (int im = 0; im < 4; ++im)
            af[im] = *(const bf16x8*)&As[cur][(waveM + im * 16 + mrow) * 32 + g8];
        for (int in = 0; in < 4; ++in)
            bf[in] = *(const bf16x8*)&Bs[cur][(waveN + in * 16 + mrow) * 32 + g8];
        for (int im = 0; im < 4; ++im)
            for (int in = 0; in < 4; ++in)
                acc[im][in] = mfma16(af[im], bf[in], acc[im][in]);
        __syncthreads();
    }

    const int rbase = (l >> 4) * 4;
    for (int im = 0; im < 4; ++im) {
        for (int in = 0; in < 4; ++in) {
            const int gm0 = tileM + waveM + im * 16 + rbase;
            const int gn = tileN + waveN + in * 16 + (l & 15);
            const float bv_ = bias[gn];
            if (MODE == 1) {
                float* out = (float*)Cout;
                for (int r = 0; r < 4; ++r)
                    out[(size_t)(gm0 + r) * ldc + gn] = acc[im][in][r] + bv_;
            } else if (tileN < 2048) {
                const float qs = (tileN < 1024) ? 0.125f * 1.4426950408889634f : 1.0f;
                u16* out = (u16*)Cout;
                for (int r = 0; r < 4; ++r)
                    out[(size_t)(gm0 + r) * 2048 + gn] = f2b((acc[im][in][r] + bv_) * qs);
            } else {
                u16* out = (u16*)Cout2;
                const int b = gm0 >> 11, s0 = gm0 & 2047;
                const int gn2 = gn - 2048;
                const int h = gn2 >> 6, dh = gn2 & 63;
                ushort4 u;
                u.x = f2b(acc[im][in][0] + bv_);
                u.y = f2b(acc[im][in][1] + bv_);
                u.z = f2b(acc[im][in][2] + bv_);
                u.w = f2b(acc[im][in][3] + bv_);
                *(ushort4*)&out[((size_t)((b * 16 + h) * 64 + dh)) * 2048 + s0] = u;
            }
        }
    }
}

// ---------------------------------------------------------------- flash attention
// R11 winner, unchanged: 256 thr = 4 waves, 128 queries/block, ONE barrier/round,
// K/V staged by global_load_lds DMA into double-buffered XOR-swizzled LDS tiles,
// max-free softmax with epilogue-only denominator reduction.
__global__ __launch_bounds__(256, 2) void attn_kernel(const u16* __restrict__ qk,
                                                      const u16* __restrict__ vt,
                                                      u16* __restrict__ attn) {
    const int bh = blockIdx.x;
    const int qt = 15 - (int)blockIdx.y;  // big q-tiles launch first
    const int b = bh >> 4, h = bh & 15;
    const int q0 = qt * 128;
    const int tid = threadIdx.x, l = tid & 63, w = tid >> 6;
    const int q = l & 15;   // query column within group
    const int g = l >> 4;   // k-group
    const int g8 = g * 8;

    __shared__ u16 Ks[2][64 * 64];  // [buf][key][dh]   XOR-swizzled chunks
    __shared__ u16 Vs[2][64 * 64];  // [buf][dh][key]   XOR-swizzled chunks
    __shared__ u16 Ps[128 * 72];    // Q staging, then per-wave P slabs [query][key]

    const int sr8 = l >> 3;
    const int gc = (l & 7) ^ sr8;
    const u16* kgl = qk + (size_t)(b * 2048 + w * 16 + sr8) * 2048 + 1024 + h * 64 + gc * 8;
    const u16* vgl = vt + (size_t)(bh * 64 + w * 16 + sr8) * 2048 + gc * 8;

    for (int i = 0; i < 4; ++i) {
        const int idx = i * 256 + tid;
        const int row = idx >> 3, ch = idx & 7;
        *(uint4*)&Ps[row * 72 + ch * 8] =
            *(const uint4*)&qk[(size_t)(b * 2048 + q0 + row) * 2048 + h * 64 + ch * 8];
    }
    for (int j = 0; j < 2; ++j) {
        gld16(kgl + (size_t)(j * 8) * 2048, &Ks[0][(w * 16 + j * 8) * 64]);
        gld16(vgl + (size_t)(j * 8) * 2048, &Vs[0][(w * 16 + j * 8) * 64]);
    }
    __syncthreads();

    bf16x8 qb[2][2];
    for (int c = 0; c < 2; ++c) {
        qb[c][0] = *(const bf16x8*)&Ps[(w * 32 + c * 16 + q) * 72 + g8];
        qb[c][1] = *(const bf16x8*)&Ps[(w * 32 + c * 16 + q) * 72 + 32 + g8];
    }

    const int cl0 = ((g) ^ (q & 7)) * 8;
    const int cl1 = ((4 + g) ^ (q & 7)) * 8;

    float li[2] = {0.f, 0.f};
    f32x4 o[2][4] = {};
    const int tmax = 2 * qt + 1;
    const int tdiag = (q0 + w * 32 + 31) >> 6;

    for (int t = 0; t <= tmax; ++t) {
        const int tp = (t < tmax) ? t + 1 : tmax;
        const int nb = (t + 1) & 1;
        for (int j = 0; j < 2; ++j) {
            gld16(kgl + (size_t)(tp * 64 + j * 8) * 2048, &Ks[nb][(w * 16 + j * 8) * 64]);
            gld16(vgl + (size_t)(j * 8) * 2048 + tp * 64, &Vs[nb][(w * 16 + j * 8) * 64]);
        }

        if (t <= tdiag) {
            const int cb0 = t & 1;
            const int kv0 = t * 64;
            const u16* ks = &Ks[cb0][0];
            const u16* vs = &Vs[cb0][0];

            f32x4 st[2][4] = {};
            for (int cb = 0; cb < 4; ++cb) {
                bf16x8 ka0 = *(const bf16x8*)&ks[(cb * 16 + q) * 64 + cl0];
                bf16x8 ka1 = *(const bf16x8*)&ks[(cb * 16 + q) * 64 + cl1];
                st[0][cb] = mfma16(ka0, qb[0][0], st[0][cb]);
                st[1][cb] = mfma16(ka0, qb[1][0], st[1][cb]);
                st[0][cb] = mfma16(ka1, qb[0][1], st[0][cb]);
                st[1][cb] = mfma16(ka1, qb[1][1], st[1][cb]);
            }
            for (int c = 0; c < 2; ++c) {
                if (t == tdiag) {
                    const int qg = q0 + w * 32 + c * 16 + q;
                    for (int cb = 0; cb < 4; ++cb)
                        for (int r = 0; r < 4; ++r) {
                            const int key = kv0 + cb * 16 + g * 4 + r;
                            if (key > qg) st[c][cb][r] = -1e30f;
                        }
                }
                float ps = 0.f;
                for (int cb = 0; cb < 4; ++cb)
                    for (int r = 0; r < 4; ++r) {
                        const float p = __builtin_amdgcn_exp2f(st[c][cb][r]);
                        st[c][cb][r] = p;
                        ps += p;
                    }
                li[c] += ps;
                for (int cb = 0; cb < 4; ++cb) {
                    ushort4 u;
                    u.x = f2b(st[c][cb][0]); u.y = f2b(st[c][cb][1]);
                    u.z = f2b(st[c][cb][2]); u.w = f2b(st[c][cb][3]);
                    *(ushort4*)&Ps[(w * 32 + c * 16 + q) * 72 + cb * 16 + g * 4] = u;
                }
            }
            __builtin_amdgcn_s_waitcnt(0xC07F);  // lgkmcnt(0)
            for (int cb = 0; cb < 4; ++cb) {
                bf16x8 va0 = *(const bf16x8*)&vs[(cb * 16 + q) * 64 + cl0];
                bf16x8 va1 = *(const bf16x8*)&vs[(cb * 16 + q) * 64 + cl1];
                bf16x8 pb00 = *(const bf16x8*)&Ps[(w * 32 + q) * 72 + g8];
                bf16x8 pb01 = *(const bf16x8*)&Ps[(w * 32 + q) * 72 + 32 + g8];
                bf16x8 pb10 = *(const bf16x8*)&Ps[(w * 32 + 16 + q) * 72 + g8];
                bf16x8 pb11 = *(const bf16x8*)&Ps[(w * 32 + 16 + q) * 72 + 32 + g8];
                o[0][cb] = mfma16(va0, pb00, o[0][cb]);
                o[1][cb] = mfma16(va0, pb10, o[1][cb]);
                o[0][cb] = mfma16(va1, pb01, o[0][cb]);
                o[1][cb] = mfma16(va1, pb11, o[1][cb]);
            }
        }
        __syncthreads();
    }

    for (int c = 0; c < 2; ++c) {
        float ps = li[c];
        ps += __shfl_xor(ps, 16);
        ps += __shfl_xor(ps, 32);
        const float inv = 1.0f / ps;
        const size_t tok = (size_t)(b * 2048 + q0 + w * 32 + c * 16 + q);
        for (int cb = 0; cb < 4; ++cb) {
            ushort4 u;
            u.x = f2b(o[c][cb][0] * inv); u.y = f2b(o[c][cb][1] * inv);
            u.z = f2b(o[c][cb][2] * inv); u.w = f2b(o[c][cb][3] * inv);
            *(ushort4*)&attn[tok * 1024 + h * 64 + cb * 16 + g * 4] = u;
        }
    }
}

// ---------------------------------------------------------------- launch
extern "C" void kernel_launch(void* const* d_in, const int* in_sizes, int n_in,
                              void* d_out, int out_size, void* d_ws, size_t ws_size,
                              hipStream_t stream) {
    const float* x  = (const float*)d_in[0];
    const float* Wq = (const float*)d_in[1];
    const float* bq = (const float*)d_in[2];
    const float* Wk = (const float*)d_in[3];
    const float* bk = (const float*)d_in[4];
    const float* Wv = (const float*)d_in[5];
    const float* bv = (const float*)d_in[6];
    const float* Wo = (const float*)d_in[7];
    const float* bo = (const float*)d_in[8];
    float* out = (float*)d_out;

    char* ws = (char*)d_ws;
    size_t off = 0;
    auto alloc = [&](size_t bytes) -> void* {
        void* p = ws + off;
        off += (bytes + 255) & ~(size_t)255;
        return p;
    };
    u16*   xb    = (u16*)alloc(8192ull * 1024 * 2);   // x bf16
    u16*   wqkvt = (u16*)alloc(3072ull * 1024 * 2);   // [Wq|Wk|Wv]^T (N,K)
    u16*   wot   = (u16*)alloc(1024ull * 1024 * 2);   // Wo^T
    float* bqkv  = (float*)alloc(3072ull * 4);
    u16*   qk    = (u16*)alloc(8192ull * 2048 * 2);   // [q|k] (token, 2048)
    u16*   vt    = (u16*)alloc(8192ull * 1024 * 2);   // V^T (B,H,Dh,S)
    u16*   attn  = (u16*)alloc(8192ull * 1024 * 2);   // attention out (token, D)

    convert_x<<<8192, 256, 0, stream>>>(x, xb, 8192 * 1024 / 4);
    transpose_w<<<dim3(32, 32, 4), dim3(32, 8), 0, stream>>>(Wq, Wk, Wv, Wo, wqkvt, wot);
    pack_bqkv<<<12, 256, 0, stream>>>(bq, bk, bv, bqkv);
    gemm256<<<dim3(32, 12), 512, 0, stream>>>(xb, wqkvt, bqkv, qk, vt, 1024);
    attn_kernel<<<dim3(64, 16), 256, 0, stream>>>(qk, vt, attn);
    gemm_bt<1><<<dim3(64, 8), 256, 0, stream>>>(attn, wot, bo, out, nullptr, 8192, 1024, 1024, 1024);
}